// Round 1
// baseline (429.925 us; speedup 1.0000x reference)
//
#include <hip/hip_runtime.h>

#define NNODES 20000
#define NEDGES 320000

__device__ __forceinline__ float leaky(float x) { return x > 0.f ? x : 0.2f * x; }
__device__ __forceinline__ float elu(float x) { return x > 0.f ? x : expm1f(x); }

__global__ void k_zero(int* __restrict__ p, int n) {
  int i = blockIdx.x * blockDim.x + threadIdx.x;
  if (i < n) p[i] = 0;
}

__global__ void k_hist(const int* __restrict__ dst, int* __restrict__ cnt, int e) {
  int i = blockIdx.x * blockDim.x + threadIdx.x;
  if (i < e) atomicAdd(&cnt[dst[i]], 1);
}

// single block, 256 threads: exclusive scan of cnt[0..n-1] -> row_start[0..n], re-zero cnt
__global__ void k_scan(int* __restrict__ cnt, int* __restrict__ row_start, int n) {
  __shared__ int s[256];
  int t = threadIdx.x;
  int chunk = (n + 255) / 256;
  int beg = t * chunk, end = min(beg + chunk, n);
  int sum = 0;
  for (int i = beg; i < end; i++) sum += cnt[i];
  s[t] = sum;
  __syncthreads();
  for (int off = 1; off < 256; off <<= 1) {
    int v = (t >= off) ? s[t - off] : 0;
    __syncthreads();
    s[t] += v;
    __syncthreads();
  }
  int run = (t == 0) ? 0 : s[t - 1];
  for (int i = beg; i < end; i++) {
    int c = cnt[i];
    row_start[i] = run;
    run += c;
    cnt[i] = 0;
  }
  if (t == 255) row_start[n] = s[255];
}

__global__ void k_scatter(const int* __restrict__ src, const int* __restrict__ dst,
                          const int* __restrict__ row_start, int* __restrict__ fill,
                          int* __restrict__ csr, int e) {
  int i = blockIdx.x * blockDim.x + threadIdx.x;
  if (i < e) {
    int d = dst[i];
    int p = row_start[d] + atomicAdd(&fill[d], 1);
    csr[p] = src[i];
  }
}

// H[nrows,OC] = A[nrows,K] @ W[K,OC]; 64x64 tile, K-chunks of 32, 4x4 register block
__global__ __launch_bounds__(256) void k_gemm(const float* __restrict__ A, const float* __restrict__ W,
                                              float* __restrict__ H, int nrows, int K, int OC) {
  __shared__ float sA[64 * 36];
  __shared__ float sW[32 * 68];
  int t = threadIdx.x;
  int n0 = blockIdx.x * 64;
  int c0 = blockIdx.y * 64;
  int tr = t >> 4, tc = t & 15;
  float acc[4][4] = {{0.f}};
  int lr = t >> 2;        // 0..63 tile row for A load
  int lk = (t & 3) * 8;   // 0,8,16,24
  int wr = t >> 3;        // 0..31 k-row for W load
  int wc = (t & 7) * 8;   // 0..56
  int arow = min(n0 + lr, nrows - 1);
  for (int kk = 0; kk < K; kk += 32) {
    float4 av0 = *(const float4*)&A[arow * K + kk + lk];
    float4 av1 = *(const float4*)&A[arow * K + kk + lk + 4];
    float4 wv0 = *(const float4*)&W[(kk + wr) * OC + c0 + wc];
    float4 wv1 = *(const float4*)&W[(kk + wr) * OC + c0 + wc + 4];
    *(float4*)&sA[lr * 36 + lk] = av0;
    *(float4*)&sA[lr * 36 + lk + 4] = av1;
    *(float4*)&sW[wr * 68 + wc] = wv0;
    *(float4*)&sW[wr * 68 + wc + 4] = wv1;
    __syncthreads();
#pragma unroll
    for (int k = 0; k < 32; k++) {
      float a0 = sA[(tr * 4 + 0) * 36 + k];
      float a1 = sA[(tr * 4 + 1) * 36 + k];
      float a2 = sA[(tr * 4 + 2) * 36 + k];
      float a3 = sA[(tr * 4 + 3) * 36 + k];
      float4 wv = *(const float4*)&sW[k * 68 + tc * 4];
      acc[0][0] += a0 * wv.x; acc[0][1] += a0 * wv.y; acc[0][2] += a0 * wv.z; acc[0][3] += a0 * wv.w;
      acc[1][0] += a1 * wv.x; acc[1][1] += a1 * wv.y; acc[1][2] += a1 * wv.z; acc[1][3] += a1 * wv.w;
      acc[2][0] += a2 * wv.x; acc[2][1] += a2 * wv.y; acc[2][2] += a2 * wv.z; acc[2][3] += a2 * wv.w;
      acc[3][0] += a3 * wv.x; acc[3][1] += a3 * wv.y; acc[3][2] += a3 * wv.z; acc[3][3] += a3 * wv.w;
    }
    __syncthreads();
  }
#pragma unroll
  for (int i = 0; i < 4; i++) {
    int row = n0 + tr * 4 + i;
    if (row < nrows) {
      float4 o = make_float4(acc[i][0], acc[i][1], acc[i][2], acc[i][3]);
      *(float4*)&H[row * OC + c0 + tc * 4] = o;
    }
  }
}

// a_s[n,h] = dot(h[n,h,:], att_src[h,:]); a_d likewise. One wave per node.
__global__ __launch_bounds__(256) void k_asd(const float* __restrict__ h, const float* __restrict__ asrc,
                                             const float* __restrict__ adst, float* __restrict__ a_s,
                                             float* __restrict__ a_d, int heads, int HC) {
  int wid = threadIdx.x >> 6, lane = threadIdx.x & 63;
  int n = blockIdx.x * 4 + wid;
  if (n >= NNODES) return;
  for (int hh = 0; hh < heads; hh++) {
    float v = h[n * HC + hh * 64 + lane];
    float ps = v * asrc[hh * 64 + lane];
    float pd = v * adst[hh * 64 + lane];
    for (int mm = 32; mm >= 1; mm >>= 1) {
      ps += __shfl_xor(ps, mm, 64);
      pd += __shfl_xor(pd, mm, 64);
    }
    if (lane == 0) {
      a_s[n * heads + hh] = ps;
      a_d[n * heads + hh] = pd;
    }
  }
}

// 4-head aggregation: one wave per dst node. lane l: head=l>>4, channels 4l..4l+3.
__global__ __launch_bounds__(256) void k_agg4(const float* __restrict__ h, const float* __restrict__ a_s,
                                              const float* __restrict__ a_d, const int* __restrict__ row_start,
                                              const int* __restrict__ csr, const float* __restrict__ bias,
                                              float* __restrict__ out) {
  int wid = threadIdx.x >> 6, lane = threadIdx.x & 63;
  int n = blockIdx.x * 4 + wid;
  if (n >= NNODES) return;
  int head = lane >> 4;
  float ad = a_d[n * 4 + head];
  float es = leaky(a_s[n * 4 + head] + ad);   // self edge
  float m = es, ssum = 1.f;
  int jb = row_start[n], je = row_start[n + 1];
  for (int j = jb; j < je; j++) {
    int src = csr[j];
    float e = leaky(a_s[src * 4 + head] + ad);
    float nm = fmaxf(m, e);
    ssum = ssum * __expf(m - nm) + __expf(e - nm);
    m = nm;
  }
  float inv = 1.f / ssum;
  float4 hv = *(const float4*)&h[n * 256 + lane * 4];
  float al = __expf(es - m) * inv;
  float4 acc = make_float4(al * hv.x, al * hv.y, al * hv.z, al * hv.w);
  for (int j = jb; j < je; j++) {
    int src = csr[j];
    float e = leaky(a_s[src * 4 + head] + ad);
    float al2 = __expf(e - m) * inv;
    float4 v = *(const float4*)&h[src * 256 + lane * 4];
    acc.x += al2 * v.x; acc.y += al2 * v.y; acc.z += al2 * v.z; acc.w += al2 * v.w;
  }
  float4 b = *(const float4*)&bias[lane * 4];
  float4 o;
  o.x = elu(acc.x + b.x); o.y = elu(acc.y + b.y);
  o.z = elu(acc.z + b.z); o.w = elu(acc.w + b.w);
  *(float4*)&out[n * 256 + lane * 4] = o;
}

// 1-head aggregation + fused MLP (64->32->1). One wave per node; lane = channel.
__global__ __launch_bounds__(256) void k_agg2(const float* __restrict__ h, const float* __restrict__ a_s,
                                              const float* __restrict__ a_d, const int* __restrict__ row_start,
                                              const int* __restrict__ csr, const float* __restrict__ bias,
                                              const float* __restrict__ w1, const float* __restrict__ b1,
                                              const float* __restrict__ w2, const float* __restrict__ b2,
                                              float* __restrict__ out) {
  __shared__ float sh[4][64];
  int wid = threadIdx.x >> 6, lane = threadIdx.x & 63;
  int n = blockIdx.x * 4 + wid;
  float val = 0.f;
  if (n < NNODES) {
    float ad = a_d[n];
    float es = leaky(a_s[n] + ad);
    float m = es, ssum = 1.f;
    int jb = row_start[n], je = row_start[n + 1];
    for (int j = jb; j < je; j++) {
      int src = csr[j];
      float e = leaky(a_s[src] + ad);
      float nm = fmaxf(m, e);
      ssum = ssum * __expf(m - nm) + __expf(e - nm);
      m = nm;
    }
    float inv = 1.f / ssum;
    float acc = __expf(es - m) * inv * h[n * 64 + lane];
    for (int j = jb; j < je; j++) {
      int src = csr[j];
      float e = leaky(a_s[src] + ad);
      acc += __expf(e - m) * inv * h[src * 64 + lane];
    }
    val = elu(acc + bias[lane]);
  }
  sh[wid][lane] = val;
  __syncthreads();
  float r = 0.f;
  if (lane < 32 && n < NNODES) {
    r = b1[lane];
#pragma unroll 8
    for (int k = 0; k < 64; k++) r += sh[wid][k] * w1[k * 32 + lane];
    r = fmaxf(r, 0.f);
    r *= w2[lane];
  }
  for (int mm = 16; mm >= 1; mm >>= 1) r += __shfl_xor(r, mm, 64);
  if (lane == 0 && n < NNODES) out[n] = r + b2[0];
}

extern "C" void kernel_launch(void* const* d_in, const int* in_sizes, int n_in,
                              void* d_out, int out_size, void* d_ws, size_t ws_size,
                              hipStream_t stream) {
  const float* x    = (const float*)d_in[0];
  const int*   eidx = (const int*)d_in[1];
  const float* lin0 = (const float*)d_in[2];
  const float* as0  = (const float*)d_in[3];
  const float* ad0  = (const float*)d_in[4];
  const float* b0   = (const float*)d_in[5];
  const float* lin1 = (const float*)d_in[6];
  const float* as1  = (const float*)d_in[7];
  const float* ad1  = (const float*)d_in[8];
  const float* b1l  = (const float*)d_in[9];
  const float* lin2 = (const float*)d_in[10];
  const float* as2  = (const float*)d_in[11];
  const float* ad2  = (const float*)d_in[12];
  const float* b2l  = (const float*)d_in[13];
  const float* w1   = (const float*)d_in[14];
  const float* mb1  = (const float*)d_in[15];
  const float* w2   = (const float*)d_in[16];
  const float* mb2  = (const float*)d_in[17];
  float* outp = (float*)d_out;

  const int* srcA = eidx;
  const int* dstA = eidx + NEDGES;

  float* bufA = (float*)d_ws;                  // [N,256] transform out (h0/h1/h2)
  float* bufB = bufA + NNODES * 256;           // [N,256] agg out (o0/o1)
  float* vas  = bufB + NNODES * 256;           // [N,4]
  float* vad  = vas + NNODES * 4;              // [N,4]
  int* row_start = (int*)(vad + NNODES * 4);   // [N+1]
  int* fill      = row_start + NNODES + 1;     // [N]
  int* csr       = fill + NNODES;              // [E]

  // Build dst-sorted CSR (self-loops handled implicitly in agg kernels)
  k_zero<<<(NNODES + 255) / 256, 256, 0, stream>>>(fill, NNODES);
  k_hist<<<(NEDGES + 255) / 256, 256, 0, stream>>>(dstA, fill, NEDGES);
  k_scan<<<1, 256, 0, stream>>>(fill, row_start, NNODES);
  k_scatter<<<(NEDGES + 255) / 256, 256, 0, stream>>>(srcA, dstA, row_start, fill, csr, NEDGES);

  dim3 g0((NNODES + 63) / 64, 4);
  // Layer 0
  k_gemm<<<g0, 256, 0, stream>>>(x, lin0, bufA, NNODES, 128, 256);
  k_asd<<<5000, 256, 0, stream>>>(bufA, as0, ad0, vas, vad, 4, 256);
  k_agg4<<<5000, 256, 0, stream>>>(bufA, vas, vad, row_start, csr, b0, bufB);
  // Layer 1
  k_gemm<<<g0, 256, 0, stream>>>(bufB, lin1, bufA, NNODES, 256, 256);
  k_asd<<<5000, 256, 0, stream>>>(bufA, as1, ad1, vas, vad, 4, 256);
  k_agg4<<<5000, 256, 0, stream>>>(bufA, vas, vad, row_start, csr, b1l, bufB);
  // Layer 2 (1 head, 64 ch) + fused MLP
  dim3 g2((NNODES + 63) / 64, 1);
  k_gemm<<<g2, 256, 0, stream>>>(bufB, lin2, bufA, NNODES, 256, 64);
  k_asd<<<5000, 256, 0, stream>>>(bufA, as2, ad2, vas, vad, 1, 64);
  k_agg2<<<5000, 256, 0, stream>>>(bufA, vas, vad, row_start, csr, b2l, w1, mb1, w2, mb2, outp);
}

// Round 2
// 415.722 us; speedup vs baseline: 1.0342x; 1.0342x over previous
//
#include <hip/hip_runtime.h>

#define NNODES 20000
#define NEDGES 320000

typedef __attribute__((ext_vector_type(8))) short bf16x8;
typedef __attribute__((ext_vector_type(4))) float f32x4;

__device__ __forceinline__ float leaky(float x) { return x > 0.f ? x : 0.2f * x; }
__device__ __forceinline__ float elu(float x) { return x > 0.f ? x : expm1f(x); }

__device__ __forceinline__ ushort f2bf(float f) {
  uint u = __float_as_uint(f);
  uint r = (u + 0x7fffu + ((u >> 16) & 1u)) >> 16;
  return (ushort)r;
}
__device__ __forceinline__ float bf2f(ushort h) {
  return __uint_as_float(((uint)h) << 16);
}

// ---------------- CSR build ----------------
__global__ void k_zero(int* __restrict__ p, int n) {
  int i = blockIdx.x * blockDim.x + threadIdx.x;
  if (i < n) p[i] = 0;
}

__global__ void k_hist(const int* __restrict__ dst, int* __restrict__ cnt, int e) {
  int i = blockIdx.x * blockDim.x + threadIdx.x;
  if (i < e) atomicAdd(&cnt[dst[i]], 1);
}

__global__ void k_scan(int* __restrict__ cnt, int* __restrict__ row_start, int n) {
  __shared__ int s[256];
  int t = threadIdx.x;
  int chunk = (n + 255) / 256;
  int beg = t * chunk, end = min(beg + chunk, n);
  int sum = 0;
  for (int i = beg; i < end; i++) sum += cnt[i];
  s[t] = sum;
  __syncthreads();
  for (int off = 1; off < 256; off <<= 1) {
    int v = (t >= off) ? s[t - off] : 0;
    __syncthreads();
    s[t] += v;
    __syncthreads();
  }
  int run = (t == 0) ? 0 : s[t - 1];
  for (int i = beg; i < end; i++) {
    int c = cnt[i];
    row_start[i] = run;
    run += c;
    cnt[i] = 0;
  }
  if (t == 255) row_start[n] = s[255];
}

__global__ void k_scatter(const int* __restrict__ src, const int* __restrict__ dst,
                          const int* __restrict__ row_start, int* __restrict__ fill,
                          int* __restrict__ csr, int* __restrict__ csrd, int e) {
  int i = blockIdx.x * blockDim.x + threadIdx.x;
  if (i < e) {
    int d = dst[i];
    int p = row_start[d] + atomicAdd(&fill[d], 1);
    csr[p] = src[i];
    csrd[p] = d;
  }
}

// ---------------- bf16 hi/lo conversion ----------------
__global__ void k_cvt(const float* __restrict__ a, ushort* __restrict__ hi,
                      ushort* __restrict__ lo, int n4) {
  int i = blockIdx.x * blockDim.x + threadIdx.x;
  if (i >= n4) return;
  float4 v = *(const float4*)&a[i * 4];
  ushort4 h, l;
  h.x = f2bf(v.x); l.x = f2bf(v.x - bf2f(h.x));
  h.y = f2bf(v.y); l.y = f2bf(v.y - bf2f(h.y));
  h.z = f2bf(v.z); l.z = f2bf(v.z - bf2f(h.z));
  h.w = f2bf(v.w); l.w = f2bf(v.w - bf2f(h.w));
  *(ushort4*)&hi[i * 4] = h;
  *(ushort4*)&lo[i * 4] = l;
}

// W[K][OC] fp32 -> Wt_hi/Wt_lo [OC][K] bf16
__global__ void k_prep_w(const float* __restrict__ w, ushort* __restrict__ th,
                         ushort* __restrict__ tl, int K, int OC) {
  int i = blockIdx.x * blockDim.x + threadIdx.x;
  if (i >= K * OC) return;
  int k = i / OC, oc = i - k * OC;
  float v = w[i];
  ushort h = f2bf(v);
  th[oc * K + k] = h;
  tl[oc * K + k] = f2bf(v - bf2f(h));
}

// ---------------- MFMA GEMM (split bf16, 3 products) ----------------
__device__ __forceinline__ bf16x8 pk(ushort4 a, ushort4 b) {
  bf16x8 v;
  v[0] = (short)a.x; v[1] = (short)a.y; v[2] = (short)a.z; v[3] = (short)a.w;
  v[4] = (short)b.x; v[5] = (short)b.y; v[6] = (short)b.z; v[7] = (short)b.w;
  return v;
}

// C[M][OC] = A[M][K] @ W[K][OC], A given as hi/lo bf16 [M][K], W as hi/lo bf16 [OC][K] (transposed).
// Block: 256 thr = 4 waves. Block tile: 64 rows x (4*NCT*16) cols. Wave w: cols [w*NCT*16, ...).
template <int NCT>
__global__ __launch_bounds__(256) void k_gemm_mfma(const ushort* __restrict__ Ah, const ushort* __restrict__ Al,
                                                   const ushort* __restrict__ Bh, const ushort* __restrict__ Bl,
                                                   float* __restrict__ C, int M, int K, int OC) {
  int w = threadIdx.x >> 6, l = threadIdx.x & 63;
  int n0 = blockIdx.x * 64;
  int cw = w * (NCT * 16);
  int lr = l & 15;
  int lk = (l >> 4) * 4;
  f32x4 acc[4][NCT];
#pragma unroll
  for (int r = 0; r < 4; r++)
#pragma unroll
    for (int t = 0; t < NCT; t++) acc[r][t] = (f32x4){0.f, 0.f, 0.f, 0.f};
  int rows[4];
#pragma unroll
  for (int r = 0; r < 4; r++) rows[r] = min(n0 + 16 * r + lr, M - 1);

  for (int k0 = 0; k0 < K; k0 += 32) {
    bf16x8 bfh[NCT], bfl[NCT];
#pragma unroll
    for (int t = 0; t < NCT; t++) {
      int col = cw + 16 * t + lr;
      const ushort* p = Bh + col * K + k0 + lk;
      bfh[t] = pk(*(const ushort4*)p, *(const ushort4*)(p + 16));
      const ushort* q = Bl + col * K + k0 + lk;
      bfl[t] = pk(*(const ushort4*)q, *(const ushort4*)(q + 16));
    }
#pragma unroll
    for (int r = 0; r < 4; r++) {
      const ushort* p = Ah + rows[r] * K + k0 + lk;
      bf16x8 ah = pk(*(const ushort4*)p, *(const ushort4*)(p + 16));
      const ushort* q = Al + rows[r] * K + k0 + lk;
      bf16x8 al = pk(*(const ushort4*)q, *(const ushort4*)(q + 16));
#pragma unroll
      for (int t = 0; t < NCT; t++) {
        acc[r][t] = __builtin_amdgcn_mfma_f32_16x16x32_bf16(ah, bfh[t], acc[r][t], 0, 0, 0);
        acc[r][t] = __builtin_amdgcn_mfma_f32_16x16x32_bf16(ah, bfl[t], acc[r][t], 0, 0, 0);
        acc[r][t] = __builtin_amdgcn_mfma_f32_16x16x32_bf16(al, bfh[t], acc[r][t], 0, 0, 0);
      }
    }
  }
  // D layout: col = l&15, row = 4*(l>>4)+reg  (within 16x16 tile)
#pragma unroll
  for (int r = 0; r < 4; r++) {
#pragma unroll
    for (int t = 0; t < NCT; t++) {
#pragma unroll
      for (int reg = 0; reg < 4; reg++) {
        int row = n0 + 16 * r + lk + reg;
        if (row < M) C[row * OC + cw + 16 * t + lr] = acc[r][t][reg];
      }
    }
  }
}

// ---------------- attention scalars ----------------
// 4 heads, HC=256: a_s[n,h] = dot(h[n,h,:], att_src[h,:])
__global__ __launch_bounds__(256) void k_asd4(const float* __restrict__ h, const float* __restrict__ asrc,
                                              const float* __restrict__ adst, float* __restrict__ a_s,
                                              float* __restrict__ a_d) {
  int wid = threadIdx.x >> 6, l = threadIdx.x & 63;
  int n = blockIdx.x * 4 + wid;
  if (n >= NNODES) return;
  int head = l >> 4;
  float4 v = *(const float4*)&h[n * 256 + l * 4];
  float4 s4 = *(const float4*)&asrc[l * 4];
  float4 d4 = *(const float4*)&adst[l * 4];
  float ps = v.x * s4.x + v.y * s4.y + v.z * s4.z + v.w * s4.w;
  float pd = v.x * d4.x + v.y * d4.y + v.z * d4.z + v.w * d4.w;
  for (int mask = 1; mask < 16; mask <<= 1) {
    ps += __shfl_xor(ps, mask, 64);
    pd += __shfl_xor(pd, mask, 64);
  }
  if ((l & 15) == 0) {
    a_s[n * 4 + head] = ps;
    a_d[n * 4 + head] = pd;
  }
}

// 1 head, HC=64
__global__ __launch_bounds__(256) void k_asd1(const float* __restrict__ h, const float* __restrict__ asrc,
                                              const float* __restrict__ adst, float* __restrict__ a_s,
                                              float* __restrict__ a_d) {
  int wid = threadIdx.x >> 6, l = threadIdx.x & 63;
  int n = blockIdx.x * 4 + wid;
  if (n >= NNODES) return;
  float v = h[n * 64 + l];
  float ps = v * asrc[l];
  float pd = v * adst[l];
  for (int mask = 1; mask < 64; mask <<= 1) {
    ps += __shfl_xor(ps, mask, 64);
    pd += __shfl_xor(pd, mask, 64);
  }
  if (l == 0) {
    a_s[n] = ps;
    a_d[n] = pd;
  }
}

// ---------------- per-edge logits (CSR order) ----------------
__global__ void k_edge4(const int* __restrict__ csr, const int* __restrict__ csrd,
                        const float* __restrict__ vas, const float* __restrict__ vad,
                        float* __restrict__ el, int e) {
  int p = blockIdx.x * blockDim.x + threadIdx.x;
  if (p >= e) return;
  int s = csr[p], d = csrd[p];
  float4 a = *(const float4*)&vas[s * 4];
  float4 b = *(const float4*)&vad[d * 4];
  float4 o;
  o.x = leaky(a.x + b.x); o.y = leaky(a.y + b.y);
  o.z = leaky(a.z + b.z); o.w = leaky(a.w + b.w);
  *(float4*)&el[p * 4] = o;
}

__global__ void k_edge1(const int* __restrict__ csr, const int* __restrict__ csrd,
                        const float* __restrict__ vas, const float* __restrict__ vad,
                        float* __restrict__ el, int e) {
  int p = blockIdx.x * blockDim.x + threadIdx.x;
  if (p >= e) return;
  el[p] = leaky(vas[csr[p]] + vad[csrd[p]]);
}

// ---------------- aggregation ----------------
// 4 heads: one wave per node. lane l: head=l>>4, sub=l&15, channels 4l..4l+3.
__global__ __launch_bounds__(256) void k_agg4(const float* __restrict__ h, const float* __restrict__ a_s,
                                              const float* __restrict__ a_d, const int* __restrict__ row_start,
                                              const int* __restrict__ csr, const float* __restrict__ el,
                                              const float* __restrict__ bias, float* __restrict__ out) {
  int wid = threadIdx.x >> 6, l = threadIdx.x & 63;
  int n = blockIdx.x * 4 + wid;
  if (n >= NNODES) return;
  int head = l >> 4, sub = l & 15;
  int jb = row_start[n], je = row_start[n + 1];
  float ad = a_d[n * 4 + head];
  float es = leaky(a_s[n * 4 + head] + ad);  // self edge
  float m = -1e30f, s = 0.f;
  if (sub == 0) { m = es; s = 1.f; }
  for (int j = jb + sub; j < je; j += 16) {
    float e = el[j * 4 + head];
    float nm = fmaxf(m, e);
    s = s * __expf(m - nm) + __expf(e - nm);
    m = nm;
  }
  for (int mask = 1; mask < 16; mask <<= 1) {
    float m2 = __shfl_xor(m, mask, 64);
    float s2 = __shfl_xor(s, mask, 64);
    float nm = fmaxf(m, m2);
    s = s * __expf(m - nm) + s2 * __expf(m2 - nm);
    m = nm;
  }
  float inv = 1.f / s;
  float4 hv = *(const float4*)&h[n * 256 + l * 4];
  float al = __expf(es - m) * inv;
  float4 acc = {al * hv.x, al * hv.y, al * hv.z, al * hv.w};
#pragma unroll 2
  for (int j = jb; j < je; j++) {
    int src = csr[j];
    float a = __expf(el[j * 4 + head] - m) * inv;
    float4 v = *(const float4*)&h[src * 256 + l * 4];
    acc.x += a * v.x; acc.y += a * v.y; acc.z += a * v.z; acc.w += a * v.w;
  }
  float4 b = *(const float4*)&bias[l * 4];
  float4 o;
  o.x = elu(acc.x + b.x); o.y = elu(acc.y + b.y);
  o.z = elu(acc.z + b.z); o.w = elu(acc.w + b.w);
  *(float4*)&out[n * 256 + l * 4] = o;
}

// 1 head + fused MLP (64->32->1)
__global__ __launch_bounds__(256) void k_agg2(const float* __restrict__ h, const float* __restrict__ a_s,
                                              const float* __restrict__ a_d, const int* __restrict__ row_start,
                                              const int* __restrict__ csr, const float* __restrict__ el,
                                              const float* __restrict__ bias,
                                              const float* __restrict__ w1, const float* __restrict__ b1,
                                              const float* __restrict__ w2, const float* __restrict__ b2,
                                              float* __restrict__ out) {
  __shared__ float sh[4][64];
  int wid = threadIdx.x >> 6, l = threadIdx.x & 63;
  int n = blockIdx.x * 4 + wid;
  float val = 0.f;
  if (n < NNODES) {
    int jb = row_start[n], je = row_start[n + 1];
    float ad = a_d[n];
    float es = leaky(a_s[n] + ad);
    float m = -1e30f, s = 0.f;
    if (l == 0) { m = es; s = 1.f; }
    for (int j = jb + l; j < je; j += 64) {
      float e = el[j];
      float nm = fmaxf(m, e);
      s = s * __expf(m - nm) + __expf(e - nm);
      m = nm;
    }
    for (int mask = 1; mask < 64; mask <<= 1) {
      float m2 = __shfl_xor(m, mask, 64);
      float s2 = __shfl_xor(s, mask, 64);
      float nm = fmaxf(m, m2);
      s = s * __expf(m - nm) + s2 * __expf(m2 - nm);
      m = nm;
    }
    float inv = 1.f / s;
    float acc = __expf(es - m) * inv * h[n * 64 + l];
    for (int j = jb; j < je; j++) {
      int src = csr[j];
      acc += __expf(el[j] - m) * inv * h[src * 64 + l];
    }
    val = elu(acc + bias[l]);
  }
  sh[wid][l] = val;
  __syncthreads();
  float r = 0.f;
  if (l < 32 && n < NNODES) {
    r = b1[l];
#pragma unroll 8
    for (int k = 0; k < 64; k++) r += sh[wid][k] * w1[k * 32 + l];
    r = fmaxf(r, 0.f);
    r *= w2[l];
  }
  for (int mask = 16; mask >= 1; mask >>= 1) r += __shfl_xor(r, mask, 64);
  if (l == 0 && n < NNODES) out[n] = r + b2[0];
}

extern "C" void kernel_launch(void* const* d_in, const int* in_sizes, int n_in,
                              void* d_out, int out_size, void* d_ws, size_t ws_size,
                              hipStream_t stream) {
  const float* x    = (const float*)d_in[0];
  const int*   eidx = (const int*)d_in[1];
  const float* lin0 = (const float*)d_in[2];
  const float* as0  = (const float*)d_in[3];
  const float* ad0  = (const float*)d_in[4];
  const float* b0   = (const float*)d_in[5];
  const float* lin1 = (const float*)d_in[6];
  const float* as1  = (const float*)d_in[7];
  const float* ad1  = (const float*)d_in[8];
  const float* b1l  = (const float*)d_in[9];
  const float* lin2 = (const float*)d_in[10];
  const float* as2  = (const float*)d_in[11];
  const float* ad2  = (const float*)d_in[12];
  const float* b2l  = (const float*)d_in[13];
  const float* w1   = (const float*)d_in[14];
  const float* mb1  = (const float*)d_in[15];
  const float* w2   = (const float*)d_in[16];
  const float* mb2  = (const float*)d_in[17];
  float* outp = (float*)d_out;

  const int* srcA = eidx;
  const int* dstA = eidx + NEDGES;

  char* ws = (char*)d_ws;
  size_t o = 0;
  auto alloc = [&](size_t bytes) { size_t r = o; o += (bytes + 255) & ~255UL; return r; };
  float*  bufA = (float*)(ws + alloc((size_t)NNODES * 256 * 4));
  float*  bufB = (float*)(ws + alloc((size_t)NNODES * 256 * 4));
  size_t  hiOff = alloc((size_t)NNODES * 256 * 2);
  ushort* hiB  = (ushort*)(ws + hiOff);
  ushort* loB  = (ushort*)(ws + alloc((size_t)NNODES * 256 * 2));
  float*  el   = (float*)(ws + hiOff);  // overlaps hiB: el live only after GEMM consumed hi/lo
  ushort* wh   = (ushort*)(ws + alloc(256 * 256 * 2));
  ushort* wl   = (ushort*)(ws + alloc(256 * 256 * 2));
  float*  vas  = (float*)(ws + alloc((size_t)NNODES * 4 * 4));
  float*  vad  = (float*)(ws + alloc((size_t)NNODES * 4 * 4));
  int* row_start = (int*)(ws + alloc((NNODES + 1) * 4));
  int* fill      = (int*)(ws + alloc(NNODES * 4));
  int* csr       = (int*)(ws + alloc(NEDGES * 4));
  int* csrd      = (int*)(ws + alloc(NEDGES * 4));

  // Build dst-sorted CSR (self-loops handled implicitly in agg kernels)
  k_zero<<<(NNODES + 255) / 256, 256, 0, stream>>>(fill, NNODES);
  k_hist<<<(NEDGES + 255) / 256, 256, 0, stream>>>(dstA, fill, NEDGES);
  k_scan<<<1, 256, 0, stream>>>(fill, row_start, NNODES);
  k_scatter<<<(NEDGES + 255) / 256, 256, 0, stream>>>(srcA, dstA, row_start, fill, csr, csrd, NEDGES);

  int gM = (NNODES + 63) / 64;
  int gE = (NEDGES + 255) / 256;

  // ---- layer 0 (IN=128 -> 4x64, concat) ----
  k_cvt<<<(NNODES * 128 / 4 + 255) / 256, 256, 0, stream>>>(x, hiB, loB, NNODES * 128 / 4);
  k_prep_w<<<(128 * 256 + 255) / 256, 256, 0, stream>>>(lin0, wh, wl, 128, 256);
  k_gemm_mfma<4><<<gM, 256, 0, stream>>>(hiB, loB, wh, wl, bufA, NNODES, 128, 256);
  k_asd4<<<5000, 256, 0, stream>>>(bufA, as0, ad0, vas, vad);
  k_edge4<<<gE, 256, 0, stream>>>(csr, csrd, vas, vad, el, NEDGES);
  k_agg4<<<5000, 256, 0, stream>>>(bufA, vas, vad, row_start, csr, el, b0, bufB);

  // ---- layer 1 (256 -> 4x64, concat) ----
  k_cvt<<<(NNODES * 256 / 4 + 255) / 256, 256, 0, stream>>>(bufB, hiB, loB, NNODES * 256 / 4);
  k_prep_w<<<(256 * 256 + 255) / 256, 256, 0, stream>>>(lin1, wh, wl, 256, 256);
  k_gemm_mfma<4><<<gM, 256, 0, stream>>>(hiB, loB, wh, wl, bufA, NNODES, 256, 256);
  k_asd4<<<5000, 256, 0, stream>>>(bufA, as1, ad1, vas, vad);
  k_edge4<<<gE, 256, 0, stream>>>(csr, csrd, vas, vad, el, NEDGES);
  k_agg4<<<5000, 256, 0, stream>>>(bufA, vas, vad, row_start, csr, el, b1l, bufB);

  // ---- layer 2 (256 -> 64, 1 head, mean) + MLP ----
  k_cvt<<<(NNODES * 256 / 4 + 255) / 256, 256, 0, stream>>>(bufB, hiB, loB, NNODES * 256 / 4);
  k_prep_w<<<(256 * 64 + 255) / 256, 256, 0, stream>>>(lin2, wh, wl, 256, 64);
  k_gemm_mfma<1><<<gM, 256, 0, stream>>>(hiB, loB, wh, wl, bufA, NNODES, 256, 64);
  k_asd1<<<5000, 256, 0, stream>>>(bufA, as2, ad2, vas, vad);
  k_edge1<<<gE, 256, 0, stream>>>(csr, csrd, vas, vad, el, NEDGES);
  k_agg2<<<5000, 256, 0, stream>>>(bufA, vas, vad, row_start, csr, el, b2l, w1, mb1, w2, mb2, outp);
}

// Round 3
// 319.229 us; speedup vs baseline: 1.3468x; 1.3023x over previous
//
#include <hip/hip_runtime.h>

#define NNODES 20000
#define NEDGES 320000

typedef __attribute__((ext_vector_type(8))) short bf16x8;
typedef __attribute__((ext_vector_type(4))) float f32x4;
typedef _Float16 f16x4 __attribute__((ext_vector_type(4)));

__device__ __forceinline__ float leaky(float x) { return x > 0.f ? x : 0.2f * x; }
__device__ __forceinline__ float elu(float x) { return x > 0.f ? x : expm1f(x); }

__device__ __forceinline__ ushort f2bf(float f) {
  uint u = __float_as_uint(f);
  uint r = (u + 0x7fffu + ((u >> 16) & 1u)) >> 16;
  return (ushort)r;
}
__device__ __forceinline__ float bf2f(ushort h) {
  return __uint_as_float(((uint)h) << 16);
}

// ---------------- CSR build ----------------
__global__ void k_zero(int* __restrict__ p, int n) {
  int i = blockIdx.x * blockDim.x + threadIdx.x;
  if (i < n) p[i] = 0;
}

__global__ void k_hist(const int* __restrict__ dst, int* __restrict__ cnt, int e) {
  int i = blockIdx.x * blockDim.x + threadIdx.x;
  if (i < e) atomicAdd(&cnt[dst[i]], 1);
}

__global__ void k_scan(int* __restrict__ cnt, int* __restrict__ row_start, int n) {
  __shared__ int s[256];
  int t = threadIdx.x;
  int chunk = (n + 255) / 256;
  int beg = t * chunk, end = min(beg + chunk, n);
  int sum = 0;
  for (int i = beg; i < end; i++) sum += cnt[i];
  s[t] = sum;
  __syncthreads();
  for (int off = 1; off < 256; off <<= 1) {
    int v = (t >= off) ? s[t - off] : 0;
    __syncthreads();
    s[t] += v;
    __syncthreads();
  }
  int run = (t == 0) ? 0 : s[t - 1];
  for (int i = beg; i < end; i++) {
    int c = cnt[i];
    row_start[i] = run;
    run += c;
    cnt[i] = 0;
  }
  if (t == 255) row_start[n] = s[255];
}

__global__ void k_scatter(const int* __restrict__ src, const int* __restrict__ dst,
                          const int* __restrict__ row_start, int* __restrict__ fill,
                          int* __restrict__ csr, int* __restrict__ csrd, int e) {
  int i = blockIdx.x * blockDim.x + threadIdx.x;
  if (i < e) {
    int d = dst[i];
    int p = row_start[d] + atomicAdd(&fill[d], 1);
    csr[p] = src[i];
    csrd[p] = d;
  }
}

// ---------------- fp32 -> packed hi/lo bf16 (MFMA fragment order) ----------------
// Within each 32-k chunk, position p = 8*g + j holds k = 4g+j (j<4) or 16+4g+(j-4).
__global__ void k_cvt_pack(const float* __restrict__ a, ushort* __restrict__ hi,
                           ushort* __restrict__ lo, int total) {
  int i = blockIdx.x * blockDim.x + threadIdx.x;
  if (i >= total) return;
  const float* src = a + (size_t)i * 32;
  ushort h[32], lw[32];
#pragma unroll
  for (int r = 0; r < 32; r++) {
    int p = (r < 16) ? ((r >> 2) * 8 + (r & 3)) : (((r - 16) >> 2) * 8 + 4 + (r & 3));
    float v = src[r];
    ushort hh = f2bf(v);
    h[p] = hh;
    lw[p] = f2bf(v - bf2f(hh));
  }
  ushort* ho = hi + (size_t)i * 32;
  ushort* llo = lo + (size_t)i * 32;
#pragma unroll
  for (int q = 0; q < 4; q++) {
    *(bf16x8*)&ho[q * 8] = *(bf16x8*)&h[q * 8];
    *(bf16x8*)&llo[q * 8] = *(bf16x8*)&lw[q * 8];
  }
}

// W[K][OC] fp32 -> packed hi/lo bf16 [OC][K]; thread per (oc, chunk)
__global__ void k_prep_w(const float* __restrict__ w, ushort* __restrict__ th,
                         ushort* __restrict__ tl, int K, int OC) {
  int i = blockIdx.x * blockDim.x + threadIdx.x;
  int KC = K / 32;
  if (i >= OC * KC) return;
  int oc = i / KC, c = i % KC;
  ushort h[32], lw[32];
#pragma unroll
  for (int r = 0; r < 32; r++) {
    int p = (r < 16) ? ((r >> 2) * 8 + (r & 3)) : (((r - 16) >> 2) * 8 + 4 + (r & 3));
    float v = w[(size_t)(c * 32 + r) * OC + oc];
    ushort hh = f2bf(v);
    h[p] = hh;
    lw[p] = f2bf(v - bf2f(hh));
  }
  ushort* ho = th + (size_t)oc * K + c * 32;
  ushort* llo = tl + (size_t)oc * K + c * 32;
#pragma unroll
  for (int q = 0; q < 4; q++) {
    *(bf16x8*)&ho[q * 8] = *(bf16x8*)&h[q * 8];
    *(bf16x8*)&llo[q * 8] = *(bf16x8*)&lw[q * 8];
  }
}

// ---------------- MFMA GEMM (split bf16, 3 products), packed fragments ----------------
// C = A[M][K] @ W[K][OC]; A,B packed hi/lo. Block: 4 waves; BM=32 (2 row tiles/wave),
// wave w covers cols [w*NCT*16, (w+1)*NCT*16). Output: fp16 H[M][OC].
template <int K, int NCT>
__global__ __launch_bounds__(256) void k_gemm_mfma(const ushort* __restrict__ Ah, const ushort* __restrict__ Al,
                                                   const ushort* __restrict__ Bh, const ushort* __restrict__ Bl,
                                                   _Float16* __restrict__ H, int M, int OC) {
  int w = threadIdx.x >> 6, l = threadIdx.x & 63;
  int n0 = blockIdx.x * 32;
  int cw = w * (NCT * 16);
  int lr = l & 15;
  int g8 = (l >> 4) * 8;
  f32x4 acc[2][NCT];
#pragma unroll
  for (int r = 0; r < 2; r++)
#pragma unroll
    for (int t = 0; t < NCT; t++) acc[r][t] = (f32x4){0.f, 0.f, 0.f, 0.f};
  int rows[2];
  rows[0] = min(n0 + lr, M - 1);
  rows[1] = min(n0 + 16 + lr, M - 1);
#pragma unroll
  for (int c = 0; c < K / 32; c++) {
    bf16x8 bh[NCT], bl[NCT];
#pragma unroll
    for (int t = 0; t < NCT; t++) {
      int col = cw + 16 * t + lr;
      bh[t] = *(const bf16x8*)(Bh + (size_t)col * K + c * 32 + g8);
      bl[t] = *(const bf16x8*)(Bl + (size_t)col * K + c * 32 + g8);
    }
#pragma unroll
    for (int r = 0; r < 2; r++) {
      bf16x8 ah = *(const bf16x8*)(Ah + (size_t)rows[r] * K + c * 32 + g8);
      bf16x8 al = *(const bf16x8*)(Al + (size_t)rows[r] * K + c * 32 + g8);
#pragma unroll
      for (int t = 0; t < NCT; t++) {
        acc[r][t] = __builtin_amdgcn_mfma_f32_16x16x32_bf16(ah, bh[t], acc[r][t], 0, 0, 0);
        acc[r][t] = __builtin_amdgcn_mfma_f32_16x16x32_bf16(al, bh[t], acc[r][t], 0, 0, 0);
        acc[r][t] = __builtin_amdgcn_mfma_f32_16x16x32_bf16(ah, bl[t], acc[r][t], 0, 0, 0);
      }
    }
  }
  // D layout: col = l&15, row = 4*(l>>4)+reg
#pragma unroll
  for (int r = 0; r < 2; r++)
#pragma unroll
    for (int t = 0; t < NCT; t++)
#pragma unroll
      for (int reg = 0; reg < 4; reg++) {
        int row = n0 + 16 * r + (l >> 4) * 4 + reg;
        if (row < M) H[(size_t)row * OC + cw + 16 * t + lr] = (_Float16)acc[r][t][reg];
      }
}

// ---------------- attention scalars (fp16 h) ----------------
__global__ __launch_bounds__(256) void k_asd4(const _Float16* __restrict__ h, const float* __restrict__ asrc,
                                              const float* __restrict__ adst, float* __restrict__ a_s,
                                              float* __restrict__ a_d) {
  int wid = threadIdx.x >> 6, l = threadIdx.x & 63;
  int n = blockIdx.x * 4 + wid;
  if (n >= NNODES) return;
  int head = l >> 4;
  f16x4 v = *(const f16x4*)&h[(size_t)n * 256 + l * 4];
  float4 s4 = *(const float4*)&asrc[l * 4];
  float4 d4 = *(const float4*)&adst[l * 4];
  float ps = (float)v[0] * s4.x + (float)v[1] * s4.y + (float)v[2] * s4.z + (float)v[3] * s4.w;
  float pd = (float)v[0] * d4.x + (float)v[1] * d4.y + (float)v[2] * d4.z + (float)v[3] * d4.w;
  for (int mask = 1; mask < 16; mask <<= 1) {
    ps += __shfl_xor(ps, mask, 64);
    pd += __shfl_xor(pd, mask, 64);
  }
  if ((l & 15) == 0) {
    a_s[n * 4 + head] = ps;
    a_d[n * 4 + head] = pd;
  }
}

__global__ __launch_bounds__(256) void k_asd1(const _Float16* __restrict__ h, const float* __restrict__ asrc,
                                              const float* __restrict__ adst, float* __restrict__ a_s,
                                              float* __restrict__ a_d) {
  int wid = threadIdx.x >> 6, l = threadIdx.x & 63;
  int n = blockIdx.x * 4 + wid;
  if (n >= NNODES) return;
  float v = (float)h[(size_t)n * 64 + l];
  float ps = v * asrc[l];
  float pd = v * adst[l];
  for (int mask = 1; mask < 64; mask <<= 1) {
    ps += __shfl_xor(ps, mask, 64);
    pd += __shfl_xor(pd, mask, 64);
  }
  if (l == 0) {
    a_s[n] = ps;
    a_d[n] = pd;
  }
}

// ---------------- per-edge logits (CSR order) ----------------
__global__ void k_edge4(const int* __restrict__ csr, const int* __restrict__ csrd,
                        const float* __restrict__ vas, const float* __restrict__ vad,
                        float* __restrict__ el, int e) {
  int p = blockIdx.x * blockDim.x + threadIdx.x;
  if (p >= e) return;
  int s = csr[p], d = csrd[p];
  float4 a = *(const float4*)&vas[s * 4];
  float4 b = *(const float4*)&vad[d * 4];
  float4 o;
  o.x = leaky(a.x + b.x); o.y = leaky(a.y + b.y);
  o.z = leaky(a.z + b.z); o.w = leaky(a.w + b.w);
  *(float4*)&el[p * 4] = o;
}

__global__ void k_edge1(const int* __restrict__ csr, const int* __restrict__ csrd,
                        const float* __restrict__ vas, const float* __restrict__ vad,
                        float* __restrict__ el, int e) {
  int p = blockIdx.x * blockDim.x + threadIdx.x;
  if (p >= e) return;
  el[p] = leaky(vas[csr[p]] + vad[csrd[p]]);
}

// ---------------- aggregation ----------------
// 4 heads: one wave per node; fp16 gather; epilogue writes packed bf16 hi/lo for next GEMM.
__global__ __launch_bounds__(256) void k_agg4(const _Float16* __restrict__ h, const float* __restrict__ a_s,
                                              const float* __restrict__ a_d, const int* __restrict__ row_start,
                                              const int* __restrict__ csr, const float* __restrict__ el,
                                              const float* __restrict__ bias,
                                              ushort* __restrict__ Ah, ushort* __restrict__ Al) {
  int wid = threadIdx.x >> 6, l = threadIdx.x & 63;
  int n = blockIdx.x * 4 + wid;
  if (n >= NNODES) return;
  int head = l >> 4, sub = l & 15;
  int jb = row_start[n], je = row_start[n + 1];
  float ad = a_d[n * 4 + head];
  float es = leaky(a_s[n * 4 + head] + ad);  // self edge
  float m = -1e30f, s = 0.f;
  if (sub == 0) { m = es; s = 1.f; }
  for (int j = jb + sub; j < je; j += 16) {
    float e = el[j * 4 + head];
    float nm = fmaxf(m, e);
    s = s * __expf(m - nm) + __expf(e - nm);
    m = nm;
  }
  for (int mask = 1; mask < 16; mask <<= 1) {
    float m2 = __shfl_xor(m, mask, 64);
    float s2 = __shfl_xor(s, mask, 64);
    float nm = fmaxf(m, m2);
    s = s * __expf(m - nm) + s2 * __expf(m2 - nm);
    m = nm;
  }
  float inv = 1.f / s;
  f16x4 hv = *(const f16x4*)&h[(size_t)n * 256 + l * 4];
  float al = __expf(es - m) * inv;
  float4 acc = {al * (float)hv[0], al * (float)hv[1], al * (float)hv[2], al * (float)hv[3]};
#pragma unroll 2
  for (int j = jb; j < je; j++) {
    int src = csr[j];
    float a = __expf(el[j * 4 + head] - m) * inv;
    f16x4 v = *(const f16x4*)&h[(size_t)src * 256 + l * 4];
    acc.x += a * (float)v[0]; acc.y += a * (float)v[1];
    acc.z += a * (float)v[2]; acc.w += a * (float)v[3];
  }
  float4 b = *(const float4*)&bias[l * 4];
  float4 o;
  o.x = elu(acc.x + b.x); o.y = elu(acc.y + b.y);
  o.z = elu(acc.z + b.z); o.w = elu(acc.w + b.w);
  // packed hi/lo write: lane l ch 4l..4l+3 -> chunk l>>3, g=l&3, j0 = (l&7)>=4 ? 4 : 0
  size_t base = (size_t)n * 256 + (l >> 3) * 32 + (l & 3) * 8 + (((l & 7) >= 4) ? 4 : 0);
  ushort4 hh, ll;
  hh.x = f2bf(o.x); ll.x = f2bf(o.x - bf2f(hh.x));
  hh.y = f2bf(o.y); ll.y = f2bf(o.y - bf2f(hh.y));
  hh.z = f2bf(o.z); ll.z = f2bf(o.z - bf2f(hh.z));
  hh.w = f2bf(o.w); ll.w = f2bf(o.w - bf2f(hh.w));
  *(ushort4*)&Ah[base] = hh;
  *(ushort4*)&Al[base] = ll;
}

// 1 head + fused MLP (64->32->1)
__global__ __launch_bounds__(256) void k_agg2(const _Float16* __restrict__ h, const float* __restrict__ a_s,
                                              const float* __restrict__ a_d, const int* __restrict__ row_start,
                                              const int* __restrict__ csr, const float* __restrict__ el,
                                              const float* __restrict__ bias,
                                              const float* __restrict__ w1, const float* __restrict__ b1,
                                              const float* __restrict__ w2, const float* __restrict__ b2,
                                              float* __restrict__ out) {
  __shared__ float sh[4][64];
  int wid = threadIdx.x >> 6, l = threadIdx.x & 63;
  int n = blockIdx.x * 4 + wid;
  float val = 0.f;
  if (n < NNODES) {
    int jb = row_start[n], je = row_start[n + 1];
    float ad = a_d[n];
    float es = leaky(a_s[n] + ad);
    float m = -1e30f, s = 0.f;
    if (l == 0) { m = es; s = 1.f; }
    for (int j = jb + l; j < je; j += 64) {
      float e = el[j];
      float nm = fmaxf(m, e);
      s = s * __expf(m - nm) + __expf(e - nm);
      m = nm;
    }
    for (int mask = 1; mask < 64; mask <<= 1) {
      float m2 = __shfl_xor(m, mask, 64);
      float s2 = __shfl_xor(s, mask, 64);
      float nm = fmaxf(m, m2);
      s = s * __expf(m - nm) + s2 * __expf(m2 - nm);
      m = nm;
    }
    float inv = 1.f / s;
    float acc = __expf(es - m) * inv * (float)h[(size_t)n * 64 + l];
    for (int j = jb; j < je; j++) {
      int src = csr[j];
      acc += __expf(el[j] - m) * inv * (float)h[(size_t)src * 64 + l];
    }
    val = elu(acc + bias[l]);
  }
  sh[wid][l] = val;
  __syncthreads();
  float r = 0.f;
  if (l < 32 && n < NNODES) {
    r = b1[l];
#pragma unroll 8
    for (int k = 0; k < 64; k++) r += sh[wid][k] * w1[k * 32 + l];
    r = fmaxf(r, 0.f);
    r *= w2[l];
  }
  for (int mask = 16; mask >= 1; mask >>= 1) r += __shfl_xor(r, mask, 64);
  if (l == 0 && n < NNODES) out[n] = r + b2[0];
}

extern "C" void kernel_launch(void* const* d_in, const int* in_sizes, int n_in,
                              void* d_out, int out_size, void* d_ws, size_t ws_size,
                              hipStream_t stream) {
  const float* x    = (const float*)d_in[0];
  const int*   eidx = (const int*)d_in[1];
  const float* lin0 = (const float*)d_in[2];
  const float* as0  = (const float*)d_in[3];
  const float* ad0  = (const float*)d_in[4];
  const float* b0   = (const float*)d_in[5];
  const float* lin1 = (const float*)d_in[6];
  const float* as1  = (const float*)d_in[7];
  const float* ad1  = (const float*)d_in[8];
  const float* b1l  = (const float*)d_in[9];
  const float* lin2 = (const float*)d_in[10];
  const float* as2  = (const float*)d_in[11];
  const float* ad2  = (const float*)d_in[12];
  const float* b2l  = (const float*)d_in[13];
  const float* w1   = (const float*)d_in[14];
  const float* mb1  = (const float*)d_in[15];
  const float* w2   = (const float*)d_in[16];
  const float* mb2  = (const float*)d_in[17];
  float* outp = (float*)d_out;

  const int* srcA = eidx;
  const int* dstA = eidx + NEDGES;

  char* ws = (char*)d_ws;
  size_t o = 0;
  auto alloc = [&](size_t bytes) { size_t r = o; o += (bytes + 255) & ~255UL; return r; };
  _Float16* h16 = (_Float16*)(ws + alloc((size_t)NNODES * 256 * 2));
  ushort* Ahp = (ushort*)(ws + alloc((size_t)NNODES * 256 * 2));
  ushort* Alp = (ushort*)(ws + alloc((size_t)NNODES * 256 * 2));
  ushort* wh  = (ushort*)(ws + alloc(256 * 256 * 2));
  ushort* wl  = (ushort*)(ws + alloc(256 * 256 * 2));
  float*  el  = (float*)(ws + alloc((size_t)NEDGES * 4 * 4));
  float*  vas = (float*)(ws + alloc((size_t)NNODES * 4 * 4));
  float*  vad = (float*)(ws + alloc((size_t)NNODES * 4 * 4));
  int* row_start = (int*)(ws + alloc((NNODES + 1) * 4));
  int* fill      = (int*)(ws + alloc(NNODES * 4));
  int* csr       = (int*)(ws + alloc(NEDGES * 4));
  int* csrd      = (int*)(ws + alloc(NEDGES * 4));

  // Build dst-sorted CSR (self-loops handled implicitly in agg kernels)
  k_zero<<<(NNODES + 255) / 256, 256, 0, stream>>>(fill, NNODES);
  k_hist<<<(NEDGES + 255) / 256, 256, 0, stream>>>(dstA, fill, NEDGES);
  k_scan<<<1, 256, 0, stream>>>(fill, row_start, NNODES);
  k_scatter<<<(NEDGES + 255) / 256, 256, 0, stream>>>(srcA, dstA, row_start, fill, csr, csrd, NEDGES);

  int gM = (NNODES + 31) / 32;          // 625 blocks for GEMM
  int gE = (NEDGES + 255) / 256;

  // ---- layer 0 (IN=128 -> 4x64, concat) ----
  k_cvt_pack<<<(NNODES * 4 + 255) / 256, 256, 0, stream>>>(x, Ahp, Alp, NNODES * 4);
  k_prep_w<<<(256 * 4 + 255) / 256, 256, 0, stream>>>(lin0, wh, wl, 128, 256);
  k_gemm_mfma<128, 4><<<gM, 256, 0, stream>>>(Ahp, Alp, wh, wl, h16, NNODES, 256);
  k_asd4<<<5000, 256, 0, stream>>>(h16, as0, ad0, vas, vad);
  k_edge4<<<gE, 256, 0, stream>>>(csr, csrd, vas, vad, el, NEDGES);
  k_agg4<<<5000, 256, 0, stream>>>(h16, vas, vad, row_start, csr, el, b0, Ahp, Alp);

  // ---- layer 1 (256 -> 4x64, concat) ----
  k_prep_w<<<(256 * 8 + 255) / 256, 256, 0, stream>>>(lin1, wh, wl, 256, 256);
  k_gemm_mfma<256, 4><<<gM, 256, 0, stream>>>(Ahp, Alp, wh, wl, h16, NNODES, 256);
  k_asd4<<<5000, 256, 0, stream>>>(h16, as1, ad1, vas, vad);
  k_edge4<<<gE, 256, 0, stream>>>(csr, csrd, vas, vad, el, NEDGES);
  k_agg4<<<5000, 256, 0, stream>>>(h16, vas, vad, row_start, csr, el, b1l, Ahp, Alp);

  // ---- layer 2 (256 -> 64, 1 head, mean) + MLP ----
  k_prep_w<<<(64 * 8 + 255) / 256, 256, 0, stream>>>(lin2, wh, wl, 256, 64);
  k_gemm_mfma<256, 1><<<gM, 256, 0, stream>>>(Ahp, Alp, wh, wl, h16, NNODES, 64);
  k_asd1<<<5000, 256, 0, stream>>>(h16, as2, ad2, vas, vad);
  k_edge1<<<gE, 256, 0, stream>>>(csr, csrd, vas, vad, el, NEDGES);
  k_agg2<<<5000, 256, 0, stream>>>(h16, vas, vad, row_start, csr, el, b2l, w1, mb1, w2, mb2, outp);
}

// Round 4
// 281.479 us; speedup vs baseline: 1.5274x; 1.1341x over previous
//
#include <hip/hip_runtime.h>

#define NNODES 20000
#define NEDGES 320000
#define SCAN_NB ((NNODES + 255) / 256)   // 79

typedef __attribute__((ext_vector_type(8))) short bf16x8;
typedef __attribute__((ext_vector_type(4))) float f32x4;
typedef _Float16 f16x4 __attribute__((ext_vector_type(4)));

__device__ __forceinline__ float leaky(float x) { return x > 0.f ? x : 0.2f * x; }
__device__ __forceinline__ float elu(float x) { return x > 0.f ? x : expm1f(x); }

__device__ __forceinline__ ushort f2bf(float f) {
  uint u = __float_as_uint(f);
  uint r = (u + 0x7fffu + ((u >> 16) & 1u)) >> 16;
  return (ushort)r;
}
__device__ __forceinline__ float bf2f(ushort h) {
  return __uint_as_float(((uint)h) << 16);
}

// ---------------- CSR build ----------------
__global__ void k_zero(int* __restrict__ p, int n) {
  int i = blockIdx.x * blockDim.x + threadIdx.x;
  if (i < n) p[i] = 0;
}

__global__ void k_hist(const int* __restrict__ dst, int* __restrict__ cnt, int e) {
  int i = blockIdx.x * blockDim.x + threadIdx.x;
  if (i < e) atomicAdd(&cnt[dst[i]], 1);
}

// stage 1: per-block exclusive scan; row_start[i] = block-local exclusive, blocksum[b] = block total
__global__ __launch_bounds__(256) void k_scan1(const int* __restrict__ cnt, int* __restrict__ row_start,
                                               int* __restrict__ blocksum, int n) {
  __shared__ int s[256];
  int t = threadIdx.x;
  int i = blockIdx.x * 256 + t;
  int v = (i < n) ? cnt[i] : 0;
  s[t] = v;
  __syncthreads();
  for (int off = 1; off < 256; off <<= 1) {
    int x = (t >= off) ? s[t - off] : 0;
    __syncthreads();
    s[t] += x;
    __syncthreads();
  }
  if (i < n) row_start[i] = s[t] - v;
  if (t == 255) blocksum[blockIdx.x] = s[255];
}

// stage 2: single block scans the block totals (SCAN_NB <= 128); writes exclusive offsets + grand total
__global__ __launch_bounds__(128) void k_scan2(int* __restrict__ blocksum, int* __restrict__ blockoff,
                                               int* __restrict__ row_start, int nb, int n) {
  __shared__ int s[128];
  int t = threadIdx.x;
  int v = (t < nb) ? blocksum[t] : 0;
  s[t] = v;
  __syncthreads();
  for (int off = 1; off < 128; off <<= 1) {
    int x = (t >= off) ? s[t - off] : 0;
    __syncthreads();
    s[t] += x;
    __syncthreads();
  }
  if (t < nb) blockoff[t] = s[t] - v;
  if (t == nb - 1) row_start[n] = s[t];
}

// stage 3: add block offsets in place; re-zero fill for scatter
__global__ __launch_bounds__(256) void k_scan3(int* __restrict__ row_start, const int* __restrict__ blockoff,
                                               int* __restrict__ fill, int n) {
  int i = blockIdx.x * 256 + threadIdx.x;
  if (i < n) {
    row_start[i] += blockoff[blockIdx.x];
    fill[i] = 0;
  }
}

__global__ void k_scatter(const int* __restrict__ src, const int* __restrict__ dst,
                          const int* __restrict__ row_start, int* __restrict__ fill,
                          int* __restrict__ csr, int* __restrict__ csrd, int e) {
  int i = blockIdx.x * blockDim.x + threadIdx.x;
  if (i < e) {
    int d = dst[i];
    int p = row_start[d] + atomicAdd(&fill[d], 1);
    csr[p] = src[i];
    csrd[p] = d;
  }
}

// ---------------- fp32 -> packed hi/lo bf16 (MFMA fragment order) ----------------
// Within each 32-k chunk, position p = 8*g + j holds k = 4g+j (j<4) or 16+4g+(j-4).
__global__ void k_cvt_pack(const float* __restrict__ a, ushort* __restrict__ hi,
                           ushort* __restrict__ lo, int total) {
  int i = blockIdx.x * blockDim.x + threadIdx.x;
  if (i >= total) return;
  const float* src = a + (size_t)i * 32;
  ushort h[32], lw[32];
#pragma unroll
  for (int r = 0; r < 32; r++) {
    int p = (r < 16) ? ((r >> 2) * 8 + (r & 3)) : (((r - 16) >> 2) * 8 + 4 + (r & 3));
    float v = src[r];
    ushort hh = f2bf(v);
    h[p] = hh;
    lw[p] = f2bf(v - bf2f(hh));
  }
  ushort* ho = hi + (size_t)i * 32;
  ushort* llo = lo + (size_t)i * 32;
#pragma unroll
  for (int q = 0; q < 4; q++) {
    *(bf16x8*)&ho[q * 8] = *(bf16x8*)&h[q * 8];
    *(bf16x8*)&llo[q * 8] = *(bf16x8*)&lw[q * 8];
  }
}

// W[K][OC] fp32 -> packed hi/lo bf16 [OC][K]; thread per (oc, chunk)
__global__ void k_prep_w(const float* __restrict__ w, ushort* __restrict__ th,
                         ushort* __restrict__ tl, int K, int OC) {
  int i = blockIdx.x * blockDim.x + threadIdx.x;
  int KC = K / 32;
  if (i >= OC * KC) return;
  int oc = i / KC, c = i % KC;
  ushort h[32], lw[32];
#pragma unroll
  for (int r = 0; r < 32; r++) {
    int p = (r < 16) ? ((r >> 2) * 8 + (r & 3)) : (((r - 16) >> 2) * 8 + 4 + (r & 3));
    float v = w[(size_t)(c * 32 + r) * OC + oc];
    ushort hh = f2bf(v);
    h[p] = hh;
    lw[p] = f2bf(v - bf2f(hh));
  }
  ushort* ho = th + (size_t)oc * K + c * 32;
  ushort* llo = tl + (size_t)oc * K + c * 32;
#pragma unroll
  for (int q = 0; q < 4; q++) {
    *(bf16x8*)&ho[q * 8] = *(bf16x8*)&h[q * 8];
    *(bf16x8*)&llo[q * 8] = *(bf16x8*)&lw[q * 8];
  }
}

// ---------------- MFMA GEMM (split bf16, 3 products), packed fragments ----------------
template <int K, int NCT>
__global__ __launch_bounds__(256) void k_gemm_mfma(const ushort* __restrict__ Ah, const ushort* __restrict__ Al,
                                                   const ushort* __restrict__ Bh, const ushort* __restrict__ Bl,
                                                   _Float16* __restrict__ H, int M, int OC) {
  int w = threadIdx.x >> 6, l = threadIdx.x & 63;
  int n0 = blockIdx.x * 32;
  int cw = w * (NCT * 16);
  int lr = l & 15;
  int g8 = (l >> 4) * 8;
  f32x4 acc[2][NCT];
#pragma unroll
  for (int r = 0; r < 2; r++)
#pragma unroll
    for (int t = 0; t < NCT; t++) acc[r][t] = (f32x4){0.f, 0.f, 0.f, 0.f};
  int rows[2];
  rows[0] = min(n0 + lr, M - 1);
  rows[1] = min(n0 + 16 + lr, M - 1);
#pragma unroll
  for (int c = 0; c < K / 32; c++) {
    bf16x8 bh[NCT], bl[NCT];
#pragma unroll
    for (int t = 0; t < NCT; t++) {
      int col = cw + 16 * t + lr;
      bh[t] = *(const bf16x8*)(Bh + (size_t)col * K + c * 32 + g8);
      bl[t] = *(const bf16x8*)(Bl + (size_t)col * K + c * 32 + g8);
    }
#pragma unroll
    for (int r = 0; r < 2; r++) {
      bf16x8 ah = *(const bf16x8*)(Ah + (size_t)rows[r] * K + c * 32 + g8);
      bf16x8 al = *(const bf16x8*)(Al + (size_t)rows[r] * K + c * 32 + g8);
#pragma unroll
      for (int t = 0; t < NCT; t++) {
        acc[r][t] = __builtin_amdgcn_mfma_f32_16x16x32_bf16(ah, bh[t], acc[r][t], 0, 0, 0);
        acc[r][t] = __builtin_amdgcn_mfma_f32_16x16x32_bf16(al, bh[t], acc[r][t], 0, 0, 0);
        acc[r][t] = __builtin_amdgcn_mfma_f32_16x16x32_bf16(ah, bl[t], acc[r][t], 0, 0, 0);
      }
    }
  }
  // D layout: col = l&15, row = 4*(l>>4)+reg
#pragma unroll
  for (int r = 0; r < 2; r++)
#pragma unroll
    for (int t = 0; t < NCT; t++)
#pragma unroll
      for (int reg = 0; reg < 4; reg++) {
        int row = n0 + 16 * r + (l >> 4) * 4 + reg;
        if (row < M) H[(size_t)row * OC + cw + 16 * t + lr] = (_Float16)acc[r][t][reg];
      }
}

// ---------------- attention scalars (fp16 h) ----------------
__global__ __launch_bounds__(256) void k_asd4(const _Float16* __restrict__ h, const float* __restrict__ asrc,
                                              const float* __restrict__ adst, float* __restrict__ a_s,
                                              float* __restrict__ a_d) {
  int wid = threadIdx.x >> 6, l = threadIdx.x & 63;
  int n = blockIdx.x * 4 + wid;
  if (n >= NNODES) return;
  int head = l >> 4;
  f16x4 v = *(const f16x4*)&h[(size_t)n * 256 + l * 4];
  float4 s4 = *(const float4*)&asrc[l * 4];
  float4 d4 = *(const float4*)&adst[l * 4];
  float ps = (float)v[0] * s4.x + (float)v[1] * s4.y + (float)v[2] * s4.z + (float)v[3] * s4.w;
  float pd = (float)v[0] * d4.x + (float)v[1] * d4.y + (float)v[2] * d4.z + (float)v[3] * d4.w;
  for (int mask = 1; mask < 16; mask <<= 1) {
    ps += __shfl_xor(ps, mask, 64);
    pd += __shfl_xor(pd, mask, 64);
  }
  if ((l & 15) == 0) {
    a_s[n * 4 + head] = ps;
    a_d[n * 4 + head] = pd;
  }
}

__global__ __launch_bounds__(256) void k_asd1(const _Float16* __restrict__ h, const float* __restrict__ asrc,
                                              const float* __restrict__ adst, float* __restrict__ a_s,
                                              float* __restrict__ a_d) {
  int wid = threadIdx.x >> 6, l = threadIdx.x & 63;
  int n = blockIdx.x * 4 + wid;
  if (n >= NNODES) return;
  float v = (float)h[(size_t)n * 64 + l];
  float ps = v * asrc[l];
  float pd = v * adst[l];
  for (int mask = 1; mask < 64; mask <<= 1) {
    ps += __shfl_xor(ps, mask, 64);
    pd += __shfl_xor(pd, mask, 64);
  }
  if (l == 0) {
    a_s[n] = ps;
    a_d[n] = pd;
  }
}

// ---------------- per-edge logits (CSR order) ----------------
__global__ void k_edge4(const int* __restrict__ csr, const int* __restrict__ csrd,
                        const float* __restrict__ vas, const float* __restrict__ vad,
                        float* __restrict__ el, int e) {
  int p = blockIdx.x * blockDim.x + threadIdx.x;
  if (p >= e) return;
  int s = csr[p], d = csrd[p];
  float4 a = *(const float4*)&vas[s * 4];
  float4 b = *(const float4*)&vad[d * 4];
  float4 o;
  o.x = leaky(a.x + b.x); o.y = leaky(a.y + b.y);
  o.z = leaky(a.z + b.z); o.w = leaky(a.w + b.w);
  *(float4*)&el[p * 4] = o;
}

__global__ void k_edge1(const int* __restrict__ csr, const int* __restrict__ csrd,
                        const float* __restrict__ vas, const float* __restrict__ vad,
                        float* __restrict__ el, int e) {
  int p = blockIdx.x * blockDim.x + threadIdx.x;
  if (p >= e) return;
  el[p] = leaky(vas[csr[p]] + vad[csrd[p]]);
}

// ---------------- aggregation ----------------
__global__ __launch_bounds__(256) void k_agg4(const _Float16* __restrict__ h, const float* __restrict__ a_s,
                                              const float* __restrict__ a_d, const int* __restrict__ row_start,
                                              const int* __restrict__ csr, const float* __restrict__ el,
                                              const float* __restrict__ bias,
                                              ushort* __restrict__ Ah, ushort* __restrict__ Al) {
  int wid = threadIdx.x >> 6, l = threadIdx.x & 63;
  int n = blockIdx.x * 4 + wid;
  if (n >= NNODES) return;
  int head = l >> 4, sub = l & 15;
  int jb = row_start[n], je = row_start[n + 1];
  float ad = a_d[n * 4 + head];
  float es = leaky(a_s[n * 4 + head] + ad);  // self edge
  float m = -1e30f, s = 0.f;
  if (sub == 0) { m = es; s = 1.f; }
  for (int j = jb + sub; j < je; j += 16) {
    float e = el[j * 4 + head];
    float nm = fmaxf(m, e);
    s = s * __expf(m - nm) + __expf(e - nm);
    m = nm;
  }
  for (int mask = 1; mask < 16; mask <<= 1) {
    float m2 = __shfl_xor(m, mask, 64);
    float s2 = __shfl_xor(s, mask, 64);
    float nm = fmaxf(m, m2);
    s = s * __expf(m - nm) + s2 * __expf(m2 - nm);
    m = nm;
  }
  float inv = 1.f / s;
  f16x4 hv = *(const f16x4*)&h[(size_t)n * 256 + l * 4];
  float al = __expf(es - m) * inv;
  float4 acc = {al * (float)hv[0], al * (float)hv[1], al * (float)hv[2], al * (float)hv[3]};
#pragma unroll 2
  for (int j = jb; j < je; j++) {
    int src = csr[j];
    float a = __expf(el[j * 4 + head] - m) * inv;
    f16x4 v = *(const f16x4*)&h[(size_t)src * 256 + l * 4];
    acc.x += a * (float)v[0]; acc.y += a * (float)v[1];
    acc.z += a * (float)v[2]; acc.w += a * (float)v[3];
  }
  float4 b = *(const float4*)&bias[l * 4];
  float4 o;
  o.x = elu(acc.x + b.x); o.y = elu(acc.y + b.y);
  o.z = elu(acc.z + b.z); o.w = elu(acc.w + b.w);
  size_t base = (size_t)n * 256 + (l >> 3) * 32 + (l & 3) * 8 + (((l & 7) >= 4) ? 4 : 0);
  ushort4 hh, ll;
  hh.x = f2bf(o.x); ll.x = f2bf(o.x - bf2f(hh.x));
  hh.y = f2bf(o.y); ll.y = f2bf(o.y - bf2f(hh.y));
  hh.z = f2bf(o.z); ll.z = f2bf(o.z - bf2f(hh.z));
  hh.w = f2bf(o.w); ll.w = f2bf(o.w - bf2f(hh.w));
  *(ushort4*)&Ah[base] = hh;
  *(ushort4*)&Al[base] = ll;
}

// 1 head + fused MLP (64->32->1)
__global__ __launch_bounds__(256) void k_agg2(const _Float16* __restrict__ h, const float* __restrict__ a_s,
                                              const float* __restrict__ a_d, const int* __restrict__ row_start,
                                              const int* __restrict__ csr, const float* __restrict__ el,
                                              const float* __restrict__ bias,
                                              const float* __restrict__ w1, const float* __restrict__ b1,
                                              const float* __restrict__ w2, const float* __restrict__ b2,
                                              float* __restrict__ out) {
  __shared__ float sh[4][64];
  int wid = threadIdx.x >> 6, l = threadIdx.x & 63;
  int n = blockIdx.x * 4 + wid;
  float val = 0.f;
  if (n < NNODES) {
    int jb = row_start[n], je = row_start[n + 1];
    float ad = a_d[n];
    float es = leaky(a_s[n] + ad);
    float m = -1e30f, s = 0.f;
    if (l == 0) { m = es; s = 1.f; }
    for (int j = jb + l; j < je; j += 64) {
      float e = el[j];
      float nm = fmaxf(m, e);
      s = s * __expf(m - nm) + __expf(e - nm);
      m = nm;
    }
    for (int mask = 1; mask < 64; mask <<= 1) {
      float m2 = __shfl_xor(m, mask, 64);
      float s2 = __shfl_xor(s, mask, 64);
      float nm = fmaxf(m, m2);
      s = s * __expf(m - nm) + s2 * __expf(m2 - nm);
      m = nm;
    }
    float inv = 1.f / s;
    float acc = __expf(es - m) * inv * (float)h[(size_t)n * 64 + l];
    for (int j = jb; j < je; j++) {
      int src = csr[j];
      acc += __expf(el[j] - m) * inv * (float)h[(size_t)src * 64 + l];
    }
    val = elu(acc + bias[l]);
  }
  sh[wid][l] = val;
  __syncthreads();
  float r = 0.f;
  if (l < 32 && n < NNODES) {
    r = b1[l];
#pragma unroll 8
    for (int k = 0; k < 64; k++) r += sh[wid][k] * w1[k * 32 + l];
    r = fmaxf(r, 0.f);
    r *= w2[l];
  }
  for (int mask = 16; mask >= 1; mask >>= 1) r += __shfl_xor(r, mask, 64);
  if (l == 0 && n < NNODES) out[n] = r + b2[0];
}

extern "C" void kernel_launch(void* const* d_in, const int* in_sizes, int n_in,
                              void* d_out, int out_size, void* d_ws, size_t ws_size,
                              hipStream_t stream) {
  const float* x    = (const float*)d_in[0];
  const int*   eidx = (const int*)d_in[1];
  const float* lin0 = (const float*)d_in[2];
  const float* as0  = (const float*)d_in[3];
  const float* ad0  = (const float*)d_in[4];
  const float* b0   = (const float*)d_in[5];
  const float* lin1 = (const float*)d_in[6];
  const float* as1  = (const float*)d_in[7];
  const float* ad1  = (const float*)d_in[8];
  const float* b1l  = (const float*)d_in[9];
  const float* lin2 = (const float*)d_in[10];
  const float* as2  = (const float*)d_in[11];
  const float* ad2  = (const float*)d_in[12];
  const float* b2l  = (const float*)d_in[13];
  const float* w1   = (const float*)d_in[14];
  const float* mb1  = (const float*)d_in[15];
  const float* w2   = (const float*)d_in[16];
  const float* mb2  = (const float*)d_in[17];
  float* outp = (float*)d_out;

  const int* srcA = eidx;
  const int* dstA = eidx + NEDGES;

  char* ws = (char*)d_ws;
  size_t o = 0;
  auto alloc = [&](size_t bytes) { size_t r = o; o += (bytes + 255) & ~255UL; return r; };
  _Float16* h16 = (_Float16*)(ws + alloc((size_t)NNODES * 256 * 2));
  ushort* Ahp = (ushort*)(ws + alloc((size_t)NNODES * 256 * 2));
  ushort* Alp = (ushort*)(ws + alloc((size_t)NNODES * 256 * 2));
  ushort* wh  = (ushort*)(ws + alloc(256 * 256 * 2));
  ushort* wl  = (ushort*)(ws + alloc(256 * 256 * 2));
  float*  el  = (float*)(ws + alloc((size_t)NEDGES * 4 * 4));
  float*  vas = (float*)(ws + alloc((size_t)NNODES * 4 * 4));
  float*  vad = (float*)(ws + alloc((size_t)NNODES * 4 * 4));
  int* row_start = (int*)(ws + alloc((NNODES + 1) * 4));
  int* fill      = (int*)(ws + alloc(NNODES * 4));
  int* csr       = (int*)(ws + alloc(NEDGES * 4));
  int* csrd      = (int*)(ws + alloc(NEDGES * 4));
  int* blocksum  = (int*)(ws + alloc(SCAN_NB * 4));
  int* blockoff  = (int*)(ws + alloc(SCAN_NB * 4));

  // Build dst-sorted CSR (self-loops handled implicitly in agg kernels)
  k_zero<<<(NNODES + 255) / 256, 256, 0, stream>>>(fill, NNODES);
  k_hist<<<(NEDGES + 255) / 256, 256, 0, stream>>>(dstA, fill, NEDGES);
  k_scan1<<<SCAN_NB, 256, 0, stream>>>(fill, row_start, blocksum, NNODES);
  k_scan2<<<1, 128, 0, stream>>>(blocksum, blockoff, row_start, SCAN_NB, NNODES);
  k_scan3<<<SCAN_NB, 256, 0, stream>>>(row_start, blockoff, fill, NNODES);
  k_scatter<<<(NEDGES + 255) / 256, 256, 0, stream>>>(srcA, dstA, row_start, fill, csr, csrd, NEDGES);

  int gM = (NNODES + 31) / 32;
  int gE = (NEDGES + 255) / 256;

  // ---- layer 0 (IN=128 -> 4x64, concat) ----
  k_cvt_pack<<<(NNODES * 4 + 255) / 256, 256, 0, stream>>>(x, Ahp, Alp, NNODES * 4);
  k_prep_w<<<(256 * 4 + 255) / 256, 256, 0, stream>>>(lin0, wh, wl, 128, 256);
  k_gemm_mfma<128, 4><<<gM, 256, 0, stream>>>(Ahp, Alp, wh, wl, h16, NNODES, 256);
  k_asd4<<<5000, 256, 0, stream>>>(h16, as0, ad0, vas, vad);
  k_edge4<<<gE, 256, 0, stream>>>(csr, csrd, vas, vad, el, NEDGES);
  k_agg4<<<5000, 256, 0, stream>>>(h16, vas, vad, row_start, csr, el, b0, Ahp, Alp);

  // ---- layer 1 (256 -> 4x64, concat) ----
  k_prep_w<<<(256 * 8 + 255) / 256, 256, 0, stream>>>(lin1, wh, wl, 256, 256);
  k_gemm_mfma<256, 4><<<gM, 256, 0, stream>>>(Ahp, Alp, wh, wl, h16, NNODES, 256);
  k_asd4<<<5000, 256, 0, stream>>>(h16, as1, ad1, vas, vad);
  k_edge4<<<gE, 256, 0, stream>>>(csr, csrd, vas, vad, el, NEDGES);
  k_agg4<<<5000, 256, 0, stream>>>(h16, vas, vad, row_start, csr, el, b1l, Ahp, Alp);

  // ---- layer 2 (256 -> 64, 1 head, mean) + MLP ----
  k_prep_w<<<(64 * 8 + 255) / 256, 256, 0, stream>>>(lin2, wh, wl, 256, 64);
  k_gemm_mfma<256, 1><<<gM, 256, 0, stream>>>(Ahp, Alp, wh, wl, h16, NNODES, 64);
  k_asd1<<<5000, 256, 0, stream>>>(h16, as2, ad2, vas, vad);
  k_edge1<<<gE, 256, 0, stream>>>(csr, csrd, vas, vad, el, NEDGES);
  k_agg2<<<5000, 256, 0, stream>>>(h16, vas, vad, row_start, csr, el, b2l, w1, mb1, w2, mb2, outp);
}

// Round 5
// 277.719 us; speedup vs baseline: 1.5481x; 1.0135x over previous
//
#include <hip/hip_runtime.h>

#define NNODES 20000
#define NEDGES 320000
#define SCAN_NB ((NNODES + 255) / 256)   // 79

typedef __attribute__((ext_vector_type(8))) short bf16x8;
typedef __attribute__((ext_vector_type(4))) float f32x4;
typedef _Float16 f16x4 __attribute__((ext_vector_type(4)));

__device__ __forceinline__ float leaky(float x) { return x > 0.f ? x : 0.2f * x; }
__device__ __forceinline__ float elu(float x) { return x > 0.f ? x : expm1f(x); }

__device__ __forceinline__ ushort f2bf(float f) {
  uint u = __float_as_uint(f);
  uint r = (u + 0x7fffu + ((u >> 16) & 1u)) >> 16;
  return (ushort)r;
}
__device__ __forceinline__ float bf2f(ushort h) {
  return __uint_as_float(((uint)h) << 16);
}

// ---------------- CSR build ----------------
__global__ void k_zero(int* __restrict__ p, int n) {
  int i = blockIdx.x * blockDim.x + threadIdx.x;
  if (i < n) p[i] = 0;
}

__global__ void k_hist(const int* __restrict__ dst, int* __restrict__ cnt, int e) {
  int i = blockIdx.x * blockDim.x + threadIdx.x;
  if (i < e) atomicAdd(&cnt[dst[i]], 1);
}

__global__ __launch_bounds__(256) void k_scan1(const int* __restrict__ cnt, int* __restrict__ row_start,
                                               int* __restrict__ blocksum, int n) {
  __shared__ int s[256];
  int t = threadIdx.x;
  int i = blockIdx.x * 256 + t;
  int v = (i < n) ? cnt[i] : 0;
  s[t] = v;
  __syncthreads();
  for (int off = 1; off < 256; off <<= 1) {
    int x = (t >= off) ? s[t - off] : 0;
    __syncthreads();
    s[t] += x;
    __syncthreads();
  }
  if (i < n) row_start[i] = s[t] - v;
  if (t == 255) blocksum[blockIdx.x] = s[255];
}

__global__ __launch_bounds__(128) void k_scan2(int* __restrict__ blocksum, int* __restrict__ blockoff,
                                               int* __restrict__ row_start, int nb, int n) {
  __shared__ int s[128];
  int t = threadIdx.x;
  int v = (t < nb) ? blocksum[t] : 0;
  s[t] = v;
  __syncthreads();
  for (int off = 1; off < 128; off <<= 1) {
    int x = (t >= off) ? s[t - off] : 0;
    __syncthreads();
    s[t] += x;
    __syncthreads();
  }
  if (t < nb) blockoff[t] = s[t] - v;
  if (t == nb - 1) row_start[n] = s[t];
}

__global__ __launch_bounds__(256) void k_scan3(int* __restrict__ row_start, const int* __restrict__ blockoff,
                                               int* __restrict__ fill, int n) {
  int i = blockIdx.x * 256 + threadIdx.x;
  if (i < n) {
    row_start[i] += blockoff[blockIdx.x];
    fill[i] = 0;
  }
}

__global__ void k_scatter(const int* __restrict__ src, const int* __restrict__ dst,
                          const int* __restrict__ row_start, int* __restrict__ fill,
                          int* __restrict__ csr, int* __restrict__ csrd, int e) {
  int i = blockIdx.x * blockDim.x + threadIdx.x;
  if (i < e) {
    int d = dst[i];
    int p = row_start[d] + atomicAdd(&fill[d], 1);
    csr[p] = src[i];
    csrd[p] = d;
  }
}

// ---------------- fp32 -> packed hi/lo bf16 (MFMA fragment order) ----------------
__global__ void k_cvt_pack(const float* __restrict__ a, ushort* __restrict__ hi,
                           ushort* __restrict__ lo, int total) {
  int i = blockIdx.x * blockDim.x + threadIdx.x;
  if (i >= total) return;
  const float* src = a + (size_t)i * 32;
  ushort h[32], lw[32];
#pragma unroll
  for (int r = 0; r < 32; r++) {
    int p = (r < 16) ? ((r >> 2) * 8 + (r & 3)) : (((r - 16) >> 2) * 8 + 4 + (r & 3));
    float v = src[r];
    ushort hh = f2bf(v);
    h[p] = hh;
    lw[p] = f2bf(v - bf2f(hh));
  }
  ushort* ho = hi + (size_t)i * 32;
  ushort* llo = lo + (size_t)i * 32;
#pragma unroll
  for (int q = 0; q < 4; q++) {
    *(bf16x8*)&ho[q * 8] = *(bf16x8*)&h[q * 8];
    *(bf16x8*)&llo[q * 8] = *(bf16x8*)&lw[q * 8];
  }
}

__global__ void k_prep_w(const float* __restrict__ w, ushort* __restrict__ th,
                         ushort* __restrict__ tl, int K, int OC) {
  int i = blockIdx.x * blockDim.x + threadIdx.x;
  int KC = K / 32;
  if (i >= OC * KC) return;
  int oc = i / KC, c = i % KC;
  ushort h[32], lw[32];
#pragma unroll
  for (int r = 0; r < 32; r++) {
    int p = (r < 16) ? ((r >> 2) * 8 + (r & 3)) : (((r - 16) >> 2) * 8 + 4 + (r & 3));
    float v = w[(size_t)(c * 32 + r) * OC + oc];
    ushort hh = f2bf(v);
    h[p] = hh;
    lw[p] = f2bf(v - bf2f(hh));
  }
  ushort* ho = th + (size_t)oc * K + c * 32;
  ushort* llo = tl + (size_t)oc * K + c * 32;
#pragma unroll
  for (int q = 0; q < 4; q++) {
    *(bf16x8*)&ho[q * 8] = *(bf16x8*)&h[q * 8];
    *(bf16x8*)&llo[q * 8] = *(bf16x8*)&lw[q * 8];
  }
}

// ---------------- MFMA GEMM (split bf16, 3 products), packed fragments ----------------
template <int K, int NCT>
__global__ __launch_bounds__(256) void k_gemm_mfma(const ushort* __restrict__ Ah, const ushort* __restrict__ Al,
                                                   const ushort* __restrict__ Bh, const ushort* __restrict__ Bl,
                                                   _Float16* __restrict__ H, int M, int OC) {
  int w = threadIdx.x >> 6, l = threadIdx.x & 63;
  int n0 = blockIdx.x * 32;
  int cw = w * (NCT * 16);
  int lr = l & 15;
  int g8 = (l >> 4) * 8;
  f32x4 acc[2][NCT];
#pragma unroll
  for (int r = 0; r < 2; r++)
#pragma unroll
    for (int t = 0; t < NCT; t++) acc[r][t] = (f32x4){0.f, 0.f, 0.f, 0.f};
  int rows[2];
  rows[0] = min(n0 + lr, M - 1);
  rows[1] = min(n0 + 16 + lr, M - 1);
#pragma unroll
  for (int c = 0; c < K / 32; c++) {
    bf16x8 bh[NCT], bl[NCT];
#pragma unroll
    for (int t = 0; t < NCT; t++) {
      int col = cw + 16 * t + lr;
      bh[t] = *(const bf16x8*)(Bh + (size_t)col * K + c * 32 + g8);
      bl[t] = *(const bf16x8*)(Bl + (size_t)col * K + c * 32 + g8);
    }
#pragma unroll
    for (int r = 0; r < 2; r++) {
      bf16x8 ah = *(const bf16x8*)(Ah + (size_t)rows[r] * K + c * 32 + g8);
      bf16x8 al = *(const bf16x8*)(Al + (size_t)rows[r] * K + c * 32 + g8);
#pragma unroll
      for (int t = 0; t < NCT; t++) {
        acc[r][t] = __builtin_amdgcn_mfma_f32_16x16x32_bf16(ah, bh[t], acc[r][t], 0, 0, 0);
        acc[r][t] = __builtin_amdgcn_mfma_f32_16x16x32_bf16(al, bh[t], acc[r][t], 0, 0, 0);
        acc[r][t] = __builtin_amdgcn_mfma_f32_16x16x32_bf16(ah, bl[t], acc[r][t], 0, 0, 0);
      }
    }
  }
#pragma unroll
  for (int r = 0; r < 2; r++)
#pragma unroll
    for (int t = 0; t < NCT; t++)
#pragma unroll
      for (int reg = 0; reg < 4; reg++) {
        int row = n0 + 16 * r + (l >> 4) * 4 + reg;
        if (row < M) H[(size_t)row * OC + cw + 16 * t + lr] = (_Float16)acc[r][t][reg];
      }
}

// ---------------- attention scalars (fp16 h) ----------------
__global__ __launch_bounds__(256) void k_asd4(const _Float16* __restrict__ h, const float* __restrict__ asrc,
                                              const float* __restrict__ adst, float* __restrict__ a_s,
                                              float* __restrict__ a_d) {
  int wid = threadIdx.x >> 6, l = threadIdx.x & 63;
  int n = blockIdx.x * 4 + wid;
  if (n >= NNODES) return;
  int head = l >> 4;
  f16x4 v = *(const f16x4*)&h[(size_t)n * 256 + l * 4];
  float4 s4 = *(const float4*)&asrc[l * 4];
  float4 d4 = *(const float4*)&adst[l * 4];
  float ps = (float)v[0] * s4.x + (float)v[1] * s4.y + (float)v[2] * s4.z + (float)v[3] * s4.w;
  float pd = (float)v[0] * d4.x + (float)v[1] * d4.y + (float)v[2] * d4.z + (float)v[3] * d4.w;
  for (int mask = 1; mask < 16; mask <<= 1) {
    ps += __shfl_xor(ps, mask, 64);
    pd += __shfl_xor(pd, mask, 64);
  }
  if ((l & 15) == 0) {
    a_s[n * 4 + head] = ps;
    a_d[n * 4 + head] = pd;
  }
}

__global__ __launch_bounds__(256) void k_asd1(const _Float16* __restrict__ h, const float* __restrict__ asrc,
                                              const float* __restrict__ adst, float* __restrict__ a_s,
                                              float* __restrict__ a_d) {
  int wid = threadIdx.x >> 6, l = threadIdx.x & 63;
  int n = blockIdx.x * 4 + wid;
  if (n >= NNODES) return;
  float v = (float)h[(size_t)n * 64 + l];
  float ps = v * asrc[l];
  float pd = v * adst[l];
  for (int mask = 1; mask < 64; mask <<= 1) {
    ps += __shfl_xor(ps, mask, 64);
    pd += __shfl_xor(pd, mask, 64);
  }
  if (l == 0) {
    a_s[n] = ps;
    a_d[n] = pd;
  }
}

// ---------------- per-edge logits, SoA by head: el[head*E + p] ----------------
__global__ void k_edge4(const int* __restrict__ csr, const int* __restrict__ csrd,
                        const float* __restrict__ vas, const float* __restrict__ vad,
                        float* __restrict__ el, int e) {
  int p = blockIdx.x * blockDim.x + threadIdx.x;
  if (p >= e) return;
  int s = csr[p], d = csrd[p];
  float4 a = *(const float4*)&vas[s * 4];
  float4 b = *(const float4*)&vad[d * 4];
  el[0 * NEDGES + p] = leaky(a.x + b.x);
  el[1 * NEDGES + p] = leaky(a.y + b.y);
  el[2 * NEDGES + p] = leaky(a.z + b.z);
  el[3 * NEDGES + p] = leaky(a.w + b.w);
}

__global__ void k_edge1(const int* __restrict__ csr, const int* __restrict__ csrd,
                        const float* __restrict__ vas, const float* __restrict__ vad,
                        float* __restrict__ el, int e) {
  int p = blockIdx.x * blockDim.x + threadIdx.x;
  if (p >= e) return;
  el[p] = leaky(vas[csr[p]] + vad[csrd[p]]);
}

// ---------------- softmax normalize: el -> alpha (in place), self-alpha -> sal ----------------
// 4 heads: one wave per node; lane: head=l>>4, sub=l&15 strides edges.
__global__ __launch_bounds__(256) void k_msal4(const float* __restrict__ a_s, const float* __restrict__ a_d,
                                               const int* __restrict__ row_start, float* __restrict__ el,
                                               float* __restrict__ sal) {
  int wid = threadIdx.x >> 6, l = threadIdx.x & 63;
  int n = blockIdx.x * 4 + wid;
  if (n >= NNODES) return;
  int head = l >> 4, sub = l & 15;
  int jb = row_start[n], je = row_start[n + 1];
  float* eh = el + (size_t)head * NEDGES;
  float ad = a_d[n * 4 + head];
  float es = leaky(a_s[n * 4 + head] + ad);
  float m = -1e30f, s = 0.f;
  if (sub == 0) { m = es; s = 1.f; }
  for (int j = jb + sub; j < je; j += 16) {
    float e = eh[j];
    float nm = fmaxf(m, e);
    s = s * __expf(m - nm) + __expf(e - nm);
    m = nm;
  }
  for (int mask = 1; mask < 16; mask <<= 1) {
    float m2 = __shfl_xor(m, mask, 64);
    float s2 = __shfl_xor(s, mask, 64);
    float nm = fmaxf(m, m2);
    s = s * __expf(m - nm) + s2 * __expf(m2 - nm);
    m = nm;
  }
  float inv = 1.f / s;
  for (int j = jb + sub; j < je; j += 16) eh[j] = __expf(eh[j] - m) * inv;
  if (sub == 0) sal[n * 4 + head] = __expf(es - m) * inv;
}

// 1 head: one wave per node; all 64 lanes stride edges.
__global__ __launch_bounds__(256) void k_msal1(const float* __restrict__ a_s, const float* __restrict__ a_d,
                                               const int* __restrict__ row_start, float* __restrict__ el,
                                               float* __restrict__ sal) {
  int wid = threadIdx.x >> 6, l = threadIdx.x & 63;
  int n = blockIdx.x * 4 + wid;
  if (n >= NNODES) return;
  int jb = row_start[n], je = row_start[n + 1];
  float ad = a_d[n];
  float es = leaky(a_s[n] + ad);
  float m = -1e30f, s = 0.f;
  if (l == 0) { m = es; s = 1.f; }
  for (int j = jb + l; j < je; j += 64) {
    float e = el[j];
    float nm = fmaxf(m, e);
    s = s * __expf(m - nm) + __expf(e - nm);
    m = nm;
  }
  for (int mask = 1; mask < 64; mask <<= 1) {
    float m2 = __shfl_xor(m, mask, 64);
    float s2 = __shfl_xor(s, mask, 64);
    float nm = fmaxf(m, m2);
    s = s * __expf(m - nm) + s2 * __expf(m2 - nm);
    m = nm;
  }
  float inv = 1.f / s;
  for (int j = jb + l; j < je; j += 64) el[j] = __expf(el[j] - m) * inv;
  if (l == 0) sal[n] = __expf(es - m) * inv;
}

// ---------------- gather-accumulate (alpha precomputed) ----------------
// 4 heads: wave per node; lane l: head=l>>4, channels 4l..4l+3. Unrolled x4 for ILP.
__global__ __launch_bounds__(256) void k_gath4(const _Float16* __restrict__ h, const int* __restrict__ row_start,
                                               const int* __restrict__ csr, const float* __restrict__ el,
                                               const float* __restrict__ sal, const float* __restrict__ bias,
                                               ushort* __restrict__ Ah, ushort* __restrict__ Al) {
  int wid = threadIdx.x >> 6, l = threadIdx.x & 63;
  int n = blockIdx.x * 4 + wid;
  if (n >= NNODES) return;
  int head = l >> 4;
  const float* eh = el + (size_t)head * NEDGES;
  int jb = row_start[n], je = row_start[n + 1];
  float sa = sal[n * 4 + head];
  f16x4 hv = *(const f16x4*)&h[(size_t)n * 256 + l * 4];
  float4 acc = {sa * (float)hv[0], sa * (float)hv[1], sa * (float)hv[2], sa * (float)hv[3]};
  int j = jb;
  for (; j + 3 < je; j += 4) {
    int s0 = csr[j], s1 = csr[j + 1], s2 = csr[j + 2], s3 = csr[j + 3];
    float a0 = eh[j], a1 = eh[j + 1], a2 = eh[j + 2], a3 = eh[j + 3];
    f16x4 v0 = *(const f16x4*)&h[(size_t)s0 * 256 + l * 4];
    f16x4 v1 = *(const f16x4*)&h[(size_t)s1 * 256 + l * 4];
    f16x4 v2 = *(const f16x4*)&h[(size_t)s2 * 256 + l * 4];
    f16x4 v3 = *(const f16x4*)&h[(size_t)s3 * 256 + l * 4];
    acc.x += a0 * (float)v0[0] + a1 * (float)v1[0] + a2 * (float)v2[0] + a3 * (float)v3[0];
    acc.y += a0 * (float)v0[1] + a1 * (float)v1[1] + a2 * (float)v2[1] + a3 * (float)v3[1];
    acc.z += a0 * (float)v0[2] + a1 * (float)v1[2] + a2 * (float)v2[2] + a3 * (float)v3[2];
    acc.w += a0 * (float)v0[3] + a1 * (float)v1[3] + a2 * (float)v2[3] + a3 * (float)v3[3];
  }
  for (; j < je; j++) {
    int s0 = csr[j];
    float a0 = eh[j];
    f16x4 v0 = *(const f16x4*)&h[(size_t)s0 * 256 + l * 4];
    acc.x += a0 * (float)v0[0]; acc.y += a0 * (float)v0[1];
    acc.z += a0 * (float)v0[2]; acc.w += a0 * (float)v0[3];
  }
  float4 b = *(const float4*)&bias[l * 4];
  float4 o;
  o.x = elu(acc.x + b.x); o.y = elu(acc.y + b.y);
  o.z = elu(acc.z + b.z); o.w = elu(acc.w + b.w);
  size_t base = (size_t)n * 256 + (l >> 3) * 32 + (l & 3) * 8 + (((l & 7) >= 4) ? 4 : 0);
  ushort4 hh, ll;
  hh.x = f2bf(o.x); ll.x = f2bf(o.x - bf2f(hh.x));
  hh.y = f2bf(o.y); ll.y = f2bf(o.y - bf2f(hh.y));
  hh.z = f2bf(o.z); ll.z = f2bf(o.z - bf2f(hh.z));
  hh.w = f2bf(o.w); ll.w = f2bf(o.w - bf2f(hh.w));
  *(ushort4*)&Ah[base] = hh;
  *(ushort4*)&Al[base] = ll;
}

// 1 head + fused MLP (64->32->1). Unrolled x4.
__global__ __launch_bounds__(256) void k_gath1(const _Float16* __restrict__ h, const int* __restrict__ row_start,
                                               const int* __restrict__ csr, const float* __restrict__ el,
                                               const float* __restrict__ sal, const float* __restrict__ bias,
                                               const float* __restrict__ w1, const float* __restrict__ b1,
                                               const float* __restrict__ w2, const float* __restrict__ b2,
                                               float* __restrict__ out) {
  __shared__ float sh[4][64];
  int wid = threadIdx.x >> 6, l = threadIdx.x & 63;
  int n = blockIdx.x * 4 + wid;
  float val = 0.f;
  if (n < NNODES) {
    int jb = row_start[n], je = row_start[n + 1];
    float acc = sal[n] * (float)h[(size_t)n * 64 + l];
    int j = jb;
    for (; j + 3 < je; j += 4) {
      int s0 = csr[j], s1 = csr[j + 1], s2 = csr[j + 2], s3 = csr[j + 3];
      float a0 = el[j], a1 = el[j + 1], a2 = el[j + 2], a3 = el[j + 3];
      float v0 = (float)h[(size_t)s0 * 64 + l];
      float v1 = (float)h[(size_t)s1 * 64 + l];
      float v2 = (float)h[(size_t)s2 * 64 + l];
      float v3 = (float)h[(size_t)s3 * 64 + l];
      acc += a0 * v0 + a1 * v1 + a2 * v2 + a3 * v3;
    }
    for (; j < je; j++) acc += el[j] * (float)h[(size_t)csr[j] * 64 + l];
    val = elu(acc + bias[l]);
  }
  sh[wid][l] = val;
  __syncthreads();
  float r = 0.f;
  if (l < 32 && n < NNODES) {
    r = b1[l];
#pragma unroll 8
    for (int k = 0; k < 64; k++) r += sh[wid][k] * w1[k * 32 + l];
    r = fmaxf(r, 0.f);
    r *= w2[l];
  }
  for (int mask = 16; mask >= 1; mask >>= 1) r += __shfl_xor(r, mask, 64);
  if (l == 0 && n < NNODES) out[n] = r + b2[0];
}

extern "C" void kernel_launch(void* const* d_in, const int* in_sizes, int n_in,
                              void* d_out, int out_size, void* d_ws, size_t ws_size,
                              hipStream_t stream) {
  const float* x    = (const float*)d_in[0];
  const int*   eidx = (const int*)d_in[1];
  const float* lin0 = (const float*)d_in[2];
  const float* as0  = (const float*)d_in[3];
  const float* ad0  = (const float*)d_in[4];
  const float* b0   = (const float*)d_in[5];
  const float* lin1 = (const float*)d_in[6];
  const float* as1  = (const float*)d_in[7];
  const float* ad1  = (const float*)d_in[8];
  const float* b1l  = (const float*)d_in[9];
  const float* lin2 = (const float*)d_in[10];
  const float* as2  = (const float*)d_in[11];
  const float* ad2  = (const float*)d_in[12];
  const float* b2l  = (const float*)d_in[13];
  const float* w1   = (const float*)d_in[14];
  const float* mb1  = (const float*)d_in[15];
  const float* w2   = (const float*)d_in[16];
  const float* mb2  = (const float*)d_in[17];
  float* outp = (float*)d_out;

  const int* srcA = eidx;
  const int* dstA = eidx + NEDGES;

  char* ws = (char*)d_ws;
  size_t o = 0;
  auto alloc = [&](size_t bytes) { size_t r = o; o += (bytes + 255) & ~255UL; return r; };
  _Float16* h16 = (_Float16*)(ws + alloc((size_t)NNODES * 256 * 2));
  ushort* Ahp = (ushort*)(ws + alloc((size_t)NNODES * 256 * 2));
  ushort* Alp = (ushort*)(ws + alloc((size_t)NNODES * 256 * 2));
  ushort* wh  = (ushort*)(ws + alloc(256 * 256 * 2));
  ushort* wl  = (ushort*)(ws + alloc(256 * 256 * 2));
  float*  el  = (float*)(ws + alloc((size_t)NEDGES * 4 * 4));
  float*  vas = (float*)(ws + alloc((size_t)NNODES * 4 * 4));
  float*  vad = (float*)(ws + alloc((size_t)NNODES * 4 * 4));
  float*  sal = (float*)(ws + alloc((size_t)NNODES * 4 * 4));
  int* row_start = (int*)(ws + alloc((NNODES + 1) * 4));
  int* fill      = (int*)(ws + alloc(NNODES * 4));
  int* csr       = (int*)(ws + alloc(NEDGES * 4));
  int* csrd      = (int*)(ws + alloc(NEDGES * 4));
  int* blocksum  = (int*)(ws + alloc(SCAN_NB * 4));
  int* blockoff  = (int*)(ws + alloc(SCAN_NB * 4));

  // Build dst-sorted CSR (self-loops handled implicitly via sal)
  k_zero<<<(NNODES + 255) / 256, 256, 0, stream>>>(fill, NNODES);
  k_hist<<<(NEDGES + 255) / 256, 256, 0, stream>>>(dstA, fill, NEDGES);
  k_scan1<<<SCAN_NB, 256, 0, stream>>>(fill, row_start, blocksum, NNODES);
  k_scan2<<<1, 128, 0, stream>>>(blocksum, blockoff, row_start, SCAN_NB, NNODES);
  k_scan3<<<SCAN_NB, 256, 0, stream>>>(row_start, blockoff, fill, NNODES);
  k_scatter<<<(NEDGES + 255) / 256, 256, 0, stream>>>(srcA, dstA, row_start, fill, csr, csrd, NEDGES);

  int gM = (NNODES + 31) / 32;
  int gE = (NEDGES + 255) / 256;

  // ---- layer 0 (IN=128 -> 4x64, concat) ----
  k_cvt_pack<<<(NNODES * 4 + 255) / 256, 256, 0, stream>>>(x, Ahp, Alp, NNODES * 4);
  k_prep_w<<<(256 * 4 + 255) / 256, 256, 0, stream>>>(lin0, wh, wl, 128, 256);
  k_gemm_mfma<128, 4><<<gM, 256, 0, stream>>>(Ahp, Alp, wh, wl, h16, NNODES, 256);
  k_asd4<<<5000, 256, 0, stream>>>(h16, as0, ad0, vas, vad);
  k_edge4<<<gE, 256, 0, stream>>>(csr, csrd, vas, vad, el, NEDGES);
  k_msal4<<<5000, 256, 0, stream>>>(vas, vad, row_start, el, sal);
  k_gath4<<<5000, 256, 0, stream>>>(h16, row_start, csr, el, sal, b0, Ahp, Alp);

  // ---- layer 1 (256 -> 4x64, concat) ----
  k_prep_w<<<(256 * 8 + 255) / 256, 256, 0, stream>>>(lin1, wh, wl, 256, 256);
  k_gemm_mfma<256, 4><<<gM, 256, 0, stream>>>(Ahp, Alp, wh, wl, h16, NNODES, 256);
  k_asd4<<<5000, 256, 0, stream>>>(h16, as1, ad1, vas, vad);
  k_edge4<<<gE, 256, 0, stream>>>(csr, csrd, vas, vad, el, NEDGES);
  k_msal4<<<5000, 256, 0, stream>>>(vas, vad, row_start, el, sal);
  k_gath4<<<5000, 256, 0, stream>>>(h16, row_start, csr, el, sal, b1l, Ahp, Alp);

  // ---- layer 2 (256 -> 64, 1 head, mean) + MLP ----
  k_prep_w<<<(64 * 8 + 255) / 256, 256, 0, stream>>>(lin2, wh, wl, 256, 64);
  k_gemm_mfma<256, 1><<<gM, 256, 0, stream>>>(Ahp, Alp, wh, wl, h16, NNODES, 64);
  k_asd1<<<5000, 256, 0, stream>>>(h16, as2, ad2, vas, vad);
  k_edge1<<<gE, 256, 0, stream>>>(csr, csrd, vas, vad, el, NEDGES);
  k_msal1<<<5000, 256, 0, stream>>>(vas, vad, row_start, el, sal);
  k_gath1<<<5000, 256, 0, stream>>>(h16, row_start, csr, el, sal, b2l, w1, mb1, w2, mb2, outp);
}

// Round 6
// 259.745 us; speedup vs baseline: 1.6552x; 1.0692x over previous
//
#include <hip/hip_runtime.h>

#define NNODES 20000
#define NEDGES 320000
#define SCAN_NB ((NNODES + 255) / 256)   // 79

typedef __attribute__((ext_vector_type(8))) short bf16x8;
typedef __attribute__((ext_vector_type(4))) float f32x4;
typedef _Float16 f16x4 __attribute__((ext_vector_type(4)));

__device__ __forceinline__ float leaky(float x) { return x > 0.f ? x : 0.2f * x; }
__device__ __forceinline__ float elu(float x) { return x > 0.f ? x : expm1f(x); }

__device__ __forceinline__ ushort f2bf(float f) {
  uint u = __float_as_uint(f);
  uint r = (u + 0x7fffu + ((u >> 16) & 1u)) >> 16;
  return (ushort)r;
}
__device__ __forceinline__ float bf2f(ushort h) {
  return __uint_as_float(((uint)h) << 16);
}

// ---------------- CSR build ----------------
__global__ void k_zero(int* __restrict__ p, int n) {
  int i = blockIdx.x * blockDim.x + threadIdx.x;
  if (i < n) p[i] = 0;
}

__global__ void k_hist(const int* __restrict__ dst, int* __restrict__ cnt, int e) {
  int i = blockIdx.x * blockDim.x + threadIdx.x;
  if (i < e) atomicAdd(&cnt[dst[i]], 1);
}

__global__ __launch_bounds__(256) void k_scan1(const int* __restrict__ cnt, int* __restrict__ row_start,
                                               int* __restrict__ blocksum, int n) {
  __shared__ int s[256];
  int t = threadIdx.x;
  int i = blockIdx.x * 256 + t;
  int v = (i < n) ? cnt[i] : 0;
  s[t] = v;
  __syncthreads();
  for (int off = 1; off < 256; off <<= 1) {
    int x = (t >= off) ? s[t - off] : 0;
    __syncthreads();
    s[t] += x;
    __syncthreads();
  }
  if (i < n) row_start[i] = s[t] - v;
  if (t == 255) blocksum[blockIdx.x] = s[255];
}

__global__ __launch_bounds__(128) void k_scan2(int* __restrict__ blocksum, int* __restrict__ blockoff,
                                               int* __restrict__ row_start, int nb, int n) {
  __shared__ int s[128];
  int t = threadIdx.x;
  int v = (t < nb) ? blocksum[t] : 0;
  s[t] = v;
  __syncthreads();
  for (int off = 1; off < 128; off <<= 1) {
    int x = (t >= off) ? s[t - off] : 0;
    __syncthreads();
    s[t] += x;
    __syncthreads();
  }
  if (t < nb) blockoff[t] = s[t] - v;
  if (t == nb - 1) row_start[n] = s[t];
}

__global__ __launch_bounds__(256) void k_scan3(int* __restrict__ row_start, const int* __restrict__ blockoff,
                                               int* __restrict__ fill, int n) {
  int i = blockIdx.x * 256 + threadIdx.x;
  if (i < n) {
    row_start[i] += blockoff[blockIdx.x];
    fill[i] = 0;
  }
}

__global__ void k_scatter(const int* __restrict__ src, const int* __restrict__ dst,
                          const int* __restrict__ row_start, int* __restrict__ fill,
                          int* __restrict__ csr, int e) {
  int i = blockIdx.x * blockDim.x + threadIdx.x;
  if (i < e) {
    int d = dst[i];
    int p = row_start[d] + atomicAdd(&fill[d], 1);
    csr[p] = src[i];
  }
}

// ---------------- fp32 -> packed hi/lo bf16 (MFMA fragment order) ----------------
__global__ void k_cvt_pack(const float* __restrict__ a, ushort* __restrict__ hi,
                           ushort* __restrict__ lo, int total) {
  int i = blockIdx.x * blockDim.x + threadIdx.x;
  if (i >= total) return;
  const float* src = a + (size_t)i * 32;
  ushort h[32], lw[32];
#pragma unroll
  for (int r = 0; r < 32; r++) {
    int p = (r < 16) ? ((r >> 2) * 8 + (r & 3)) : (((r - 16) >> 2) * 8 + 4 + (r & 3));
    float v = src[r];
    ushort hh = f2bf(v);
    h[p] = hh;
    lw[p] = f2bf(v - bf2f(hh));
  }
  ushort* ho = hi + (size_t)i * 32;
  ushort* llo = lo + (size_t)i * 32;
#pragma unroll
  for (int q = 0; q < 4; q++) {
    *(bf16x8*)&ho[q * 8] = *(bf16x8*)&h[q * 8];
    *(bf16x8*)&llo[q * 8] = *(bf16x8*)&lw[q * 8];
  }
}

__global__ void k_prep_w(const float* __restrict__ w, ushort* __restrict__ th,
                         ushort* __restrict__ tl, int K, int OC) {
  int i = blockIdx.x * blockDim.x + threadIdx.x;
  int KC = K / 32;
  if (i >= OC * KC) return;
  int oc = i / KC, c = i % KC;
  ushort h[32], lw[32];
#pragma unroll
  for (int r = 0; r < 32; r++) {
    int p = (r < 16) ? ((r >> 2) * 8 + (r & 3)) : (((r - 16) >> 2) * 8 + 4 + (r & 3));
    float v = w[(size_t)(c * 32 + r) * OC + oc];
    ushort hh = f2bf(v);
    h[p] = hh;
    lw[p] = f2bf(v - bf2f(hh));
  }
  ushort* ho = th + (size_t)oc * K + c * 32;
  ushort* llo = tl + (size_t)oc * K + c * 32;
#pragma unroll
  for (int q = 0; q < 4; q++) {
    *(bf16x8*)&ho[q * 8] = *(bf16x8*)&h[q * 8];
    *(bf16x8*)&llo[q * 8] = *(bf16x8*)&lw[q * 8];
  }
}

// ---------------- MFMA GEMM + fused attention-scalar epilogue ----------------
// HEADS==4: OC=256, NCT=4 -> wave w owns cols [64w,64w+64) == head w; per-row 16-lane
// shfl reduce yields dot(h[n,head,:], att) with no extra global reads.
// HEADS==1: OC=64, NCT=1 -> partial per wave, cross-wave combine via 1KB LDS.
template <int K, int NCT, int HEADS>
__global__ __launch_bounds__(256) void k_gemm_mfma(const ushort* __restrict__ Ah, const ushort* __restrict__ Al,
                                                   const ushort* __restrict__ Bh, const ushort* __restrict__ Bl,
                                                   const float* __restrict__ asrc, const float* __restrict__ adst,
                                                   _Float16* __restrict__ H, float* __restrict__ a_s,
                                                   float* __restrict__ a_d, int M, int OC) {
  __shared__ float sh_s[4][32], sh_d[4][32];
  int w = threadIdx.x >> 6, l = threadIdx.x & 63;
  int n0 = blockIdx.x * 32;
  int cw = w * (NCT * 16);
  int lr = l & 15;
  int g8 = (l >> 4) * 8;
  f32x4 acc[2][NCT];
#pragma unroll
  for (int r = 0; r < 2; r++)
#pragma unroll
    for (int t = 0; t < NCT; t++) acc[r][t] = (f32x4){0.f, 0.f, 0.f, 0.f};
  int rows[2];
  rows[0] = min(n0 + lr, M - 1);
  rows[1] = min(n0 + 16 + lr, M - 1);
#pragma unroll
  for (int c = 0; c < K / 32; c++) {
    bf16x8 bh[NCT], bl[NCT];
#pragma unroll
    for (int t = 0; t < NCT; t++) {
      int col = cw + 16 * t + lr;
      bh[t] = *(const bf16x8*)(Bh + (size_t)col * K + c * 32 + g8);
      bl[t] = *(const bf16x8*)(Bl + (size_t)col * K + c * 32 + g8);
    }
#pragma unroll
    for (int r = 0; r < 2; r++) {
      bf16x8 ah = *(const bf16x8*)(Ah + (size_t)rows[r] * K + c * 32 + g8);
      bf16x8 al = *(const bf16x8*)(Al + (size_t)rows[r] * K + c * 32 + g8);
#pragma unroll
      for (int t = 0; t < NCT; t++) {
        acc[r][t] = __builtin_amdgcn_mfma_f32_16x16x32_bf16(ah, bh[t], acc[r][t], 0, 0, 0);
        acc[r][t] = __builtin_amdgcn_mfma_f32_16x16x32_bf16(al, bh[t], acc[r][t], 0, 0, 0);
        acc[r][t] = __builtin_amdgcn_mfma_f32_16x16x32_bf16(ah, bl[t], acc[r][t], 0, 0, 0);
      }
    }
  }
  // H write (D layout: col = l&15, row = 4*(l>>4)+reg)
#pragma unroll
  for (int r = 0; r < 2; r++)
#pragma unroll
    for (int t = 0; t < NCT; t++)
#pragma unroll
      for (int reg = 0; reg < 4; reg++) {
        int row = n0 + 16 * r + (l >> 4) * 4 + reg;
        if (row < M) H[(size_t)row * OC + cw + 16 * t + lr] = (_Float16)acc[r][t][reg];
      }
  // fused attention scalars
  float asv[NCT], adv[NCT];
#pragma unroll
  for (int t = 0; t < NCT; t++) {
    asv[t] = asrc[cw + 16 * t + lr];
    adv[t] = adst[cw + 16 * t + lr];
  }
#pragma unroll
  for (int r = 0; r < 2; r++) {
#pragma unroll
    for (int reg = 0; reg < 4; reg++) {
      float ps = 0.f, pd = 0.f;
#pragma unroll
      for (int t = 0; t < NCT; t++) {
        ps += acc[r][t][reg] * asv[t];
        pd += acc[r][t][reg] * adv[t];
      }
#pragma unroll
      for (int mask = 1; mask < 16; mask <<= 1) {
        ps += __shfl_xor(ps, mask, 64);
        pd += __shfl_xor(pd, mask, 64);
      }
      int rl = 16 * r + (l >> 4) * 4 + reg;
      if (HEADS == 4) {
        if (lr == 0) {
          int row = n0 + rl;
          if (row < M) { a_s[row * 4 + w] = ps; a_d[row * 4 + w] = pd; }
        }
      } else {
        if (lr == 0) { sh_s[w][rl] = ps; sh_d[w][rl] = pd; }
      }
    }
  }
  if (HEADS == 1) {
    __syncthreads();
    int tid = threadIdx.x;
    if (tid < 32) {
      int row = n0 + tid;
      if (row < M) {
        a_s[row] = sh_s[0][tid] + sh_s[1][tid] + sh_s[2][tid] + sh_s[3][tid];
        a_d[row] = sh_d[0][tid] + sh_d[1][tid] + sh_d[2][tid] + sh_d[3][tid];
      }
    }
  }
}

// ---------------- fused edge-logit + segment softmax -> alpha (SoA by head) ----------------
// 4 heads: one wave per node. lane: head=l>>4, sub=l&15 strides the node's edges.
__global__ __launch_bounds__(256) void k_alpha4(const float* __restrict__ a_s, const float* __restrict__ a_d,
                                                const int* __restrict__ row_start, const int* __restrict__ csr,
                                                float* __restrict__ el, float* __restrict__ sal) {
  int wid = threadIdx.x >> 6, l = threadIdx.x & 63;
  int n = blockIdx.x * 4 + wid;
  if (n >= NNODES) return;
  int head = l >> 4, sub = l & 15;
  int jb = row_start[n], je = row_start[n + 1];
  float ad = a_d[n * 4 + head];
  float es = leaky(a_s[n * 4 + head] + ad);
  float m = -1e30f, s = 0.f;
  if (sub == 0) { m = es; s = 1.f; }
  for (int j = jb + sub; j < je; j += 16) {
    float e = leaky(a_s[csr[j] * 4 + head] + ad);
    float nm = fmaxf(m, e);
    s = s * __expf(m - nm) + __expf(e - nm);
    m = nm;
  }
#pragma unroll
  for (int mask = 1; mask < 16; mask <<= 1) {
    float m2 = __shfl_xor(m, mask, 64);
    float s2 = __shfl_xor(s, mask, 64);
    float nm = fmaxf(m, m2);
    s = s * __expf(m - nm) + s2 * __expf(m2 - nm);
    m = nm;
  }
  float inv = 1.f / s;
  float* eh = el + (size_t)head * NEDGES;
  for (int j = jb + sub; j < je; j += 16) {
    float e = leaky(a_s[csr[j] * 4 + head] + ad);
    eh[j] = __expf(e - m) * inv;
  }
  if (sub == 0) sal[n * 4 + head] = __expf(es - m) * inv;
}

// 1 head: one wave per node; all 64 lanes stride edges.
__global__ __launch_bounds__(256) void k_alpha1(const float* __restrict__ a_s, const float* __restrict__ a_d,
                                                const int* __restrict__ row_start, const int* __restrict__ csr,
                                                float* __restrict__ el, float* __restrict__ sal) {
  int wid = threadIdx.x >> 6, l = threadIdx.x & 63;
  int n = blockIdx.x * 4 + wid;
  if (n >= NNODES) return;
  int jb = row_start[n], je = row_start[n + 1];
  float ad = a_d[n];
  float es = leaky(a_s[n] + ad);
  float m = -1e30f, s = 0.f;
  if (l == 0) { m = es; s = 1.f; }
  for (int j = jb + l; j < je; j += 64) {
    float e = leaky(a_s[csr[j]] + ad);
    float nm = fmaxf(m, e);
    s = s * __expf(m - nm) + __expf(e - nm);
    m = nm;
  }
#pragma unroll
  for (int mask = 1; mask < 64; mask <<= 1) {
    float m2 = __shfl_xor(m, mask, 64);
    float s2 = __shfl_xor(s, mask, 64);
    float nm = fmaxf(m, m2);
    s = s * __expf(m - nm) + s2 * __expf(m2 - nm);
    m = nm;
  }
  float inv = 1.f / s;
  for (int j = jb + l; j < je; j += 64) el[j] = __expf(leaky(a_s[csr[j]] + ad) - m) * inv;
  if (l == 0) sal[n] = __expf(es - m) * inv;
}

// ---------------- gather-accumulate (alpha precomputed) ----------------
__global__ __launch_bounds__(256) void k_gath4(const _Float16* __restrict__ h, const int* __restrict__ row_start,
                                               const int* __restrict__ csr, const float* __restrict__ el,
                                               const float* __restrict__ sal, const float* __restrict__ bias,
                                               ushort* __restrict__ Ah, ushort* __restrict__ Al) {
  int wid = threadIdx.x >> 6, l = threadIdx.x & 63;
  int n = blockIdx.x * 4 + wid;
  if (n >= NNODES) return;
  int head = l >> 4;
  const float* eh = el + (size_t)head * NEDGES;
  int jb = row_start[n], je = row_start[n + 1];
  float sa = sal[n * 4 + head];
  f16x4 hv = *(const f16x4*)&h[(size_t)n * 256 + l * 4];
  float4 acc = {sa * (float)hv[0], sa * (float)hv[1], sa * (float)hv[2], sa * (float)hv[3]};
  int j = jb;
  for (; j + 3 < je; j += 4) {
    int s0 = csr[j], s1 = csr[j + 1], s2 = csr[j + 2], s3 = csr[j + 3];
    float a0 = eh[j], a1 = eh[j + 1], a2 = eh[j + 2], a3 = eh[j + 3];
    f16x4 v0 = *(const f16x4*)&h[(size_t)s0 * 256 + l * 4];
    f16x4 v1 = *(const f16x4*)&h[(size_t)s1 * 256 + l * 4];
    f16x4 v2 = *(const f16x4*)&h[(size_t)s2 * 256 + l * 4];
    f16x4 v3 = *(const f16x4*)&h[(size_t)s3 * 256 + l * 4];
    acc.x += a0 * (float)v0[0] + a1 * (float)v1[0] + a2 * (float)v2[0] + a3 * (float)v3[0];
    acc.y += a0 * (float)v0[1] + a1 * (float)v1[1] + a2 * (float)v2[1] + a3 * (float)v3[1];
    acc.z += a0 * (float)v0[2] + a1 * (float)v1[2] + a2 * (float)v2[2] + a3 * (float)v3[2];
    acc.w += a0 * (float)v0[3] + a1 * (float)v1[3] + a2 * (float)v2[3] + a3 * (float)v3[3];
  }
  for (; j < je; j++) {
    int s0 = csr[j];
    float a0 = eh[j];
    f16x4 v0 = *(const f16x4*)&h[(size_t)s0 * 256 + l * 4];
    acc.x += a0 * (float)v0[0]; acc.y += a0 * (float)v0[1];
    acc.z += a0 * (float)v0[2]; acc.w += a0 * (float)v0[3];
  }
  float4 b = *(const float4*)&bias[l * 4];
  float4 o;
  o.x = elu(acc.x + b.x); o.y = elu(acc.y + b.y);
  o.z = elu(acc.z + b.z); o.w = elu(acc.w + b.w);
  size_t base = (size_t)n * 256 + (l >> 3) * 32 + (l & 3) * 8 + (((l & 7) >= 4) ? 4 : 0);
  ushort4 hh, ll;
  hh.x = f2bf(o.x); ll.x = f2bf(o.x - bf2f(hh.x));
  hh.y = f2bf(o.y); ll.y = f2bf(o.y - bf2f(hh.y));
  hh.z = f2bf(o.z); ll.z = f2bf(o.z - bf2f(hh.z));
  hh.w = f2bf(o.w); ll.w = f2bf(o.w - bf2f(hh.w));
  *(ushort4*)&Ah[base] = hh;
  *(ushort4*)&Al[base] = ll;
}

// 1 head + fused MLP (64->32->1)
__global__ __launch_bounds__(256) void k_gath1(const _Float16* __restrict__ h, const int* __restrict__ row_start,
                                               const int* __restrict__ csr, const float* __restrict__ el,
                                               const float* __restrict__ sal, const float* __restrict__ bias,
                                               const float* __restrict__ w1, const float* __restrict__ b1,
                                               const float* __restrict__ w2, const float* __restrict__ b2,
                                               float* __restrict__ out) {
  __shared__ float sh[4][64];
  int wid = threadIdx.x >> 6, l = threadIdx.x & 63;
  int n = blockIdx.x * 4 + wid;
  float val = 0.f;
  if (n < NNODES) {
    int jb = row_start[n], je = row_start[n + 1];
    float acc = sal[n] * (float)h[(size_t)n * 64 + l];
    int j = jb;
    for (; j + 3 < je; j += 4) {
      int s0 = csr[j], s1 = csr[j + 1], s2 = csr[j + 2], s3 = csr[j + 3];
      float a0 = el[j], a1 = el[j + 1], a2 = el[j + 2], a3 = el[j + 3];
      float v0 = (float)h[(size_t)s0 * 64 + l];
      float v1 = (float)h[(size_t)s1 * 64 + l];
      float v2 = (float)h[(size_t)s2 * 64 + l];
      float v3 = (float)h[(size_t)s3 * 64 + l];
      acc += a0 * v0 + a1 * v1 + a2 * v2 + a3 * v3;
    }
    for (; j < je; j++) acc += el[j] * (float)h[(size_t)csr[j] * 64 + l];
    val = elu(acc + bias[l]);
  }
  sh[wid][l] = val;
  __syncthreads();
  float r = 0.f;
  if (l < 32 && n < NNODES) {
    r = b1[l];
#pragma unroll 8
    for (int k = 0; k < 64; k++) r += sh[wid][k] * w1[k * 32 + l];
    r = fmaxf(r, 0.f);
    r *= w2[l];
  }
  for (int mask = 16; mask >= 1; mask >>= 1) r += __shfl_xor(r, mask, 64);
  if (l == 0 && n < NNODES) out[n] = r + b2[0];
}

extern "C" void kernel_launch(void* const* d_in, const int* in_sizes, int n_in,
                              void* d_out, int out_size, void* d_ws, size_t ws_size,
                              hipStream_t stream) {
  const float* x    = (const float*)d_in[0];
  const int*   eidx = (const int*)d_in[1];
  const float* lin0 = (const float*)d_in[2];
  const float* as0  = (const float*)d_in[3];
  const float* ad0  = (const float*)d_in[4];
  const float* b0   = (const float*)d_in[5];
  const float* lin1 = (const float*)d_in[6];
  const float* as1  = (const float*)d_in[7];
  const float* ad1  = (const float*)d_in[8];
  const float* b1l  = (const float*)d_in[9];
  const float* lin2 = (const float*)d_in[10];
  const float* as2  = (const float*)d_in[11];
  const float* ad2  = (const float*)d_in[12];
  const float* b2l  = (const float*)d_in[13];
  const float* w1   = (const float*)d_in[14];
  const float* mb1  = (const float*)d_in[15];
  const float* w2   = (const float*)d_in[16];
  const float* mb2  = (const float*)d_in[17];
  float* outp = (float*)d_out;

  const int* srcA = eidx;
  const int* dstA = eidx + NEDGES;

  char* ws = (char*)d_ws;
  size_t o = 0;
  auto alloc = [&](size_t bytes) { size_t r = o; o += (bytes + 255) & ~255UL; return r; };
  _Float16* h16 = (_Float16*)(ws + alloc((size_t)NNODES * 256 * 2));
  ushort* Ahp = (ushort*)(ws + alloc((size_t)NNODES * 256 * 2));
  ushort* Alp = (ushort*)(ws + alloc((size_t)NNODES * 256 * 2));
  ushort* wh  = (ushort*)(ws + alloc(256 * 256 * 2));
  ushort* wl  = (ushort*)(ws + alloc(256 * 256 * 2));
  float*  el  = (float*)(ws + alloc((size_t)NEDGES * 4 * 4));
  float*  vas = (float*)(ws + alloc((size_t)NNODES * 4 * 4));
  float*  vad = (float*)(ws + alloc((size_t)NNODES * 4 * 4));
  float*  sal = (float*)(ws + alloc((size_t)NNODES * 4 * 4));
  int* row_start = (int*)(ws + alloc((NNODES + 1) * 4));
  int* fill      = (int*)(ws + alloc(NNODES * 4));
  int* csr       = (int*)(ws + alloc(NEDGES * 4));
  int* blocksum  = (int*)(ws + alloc(SCAN_NB * 4));
  int* blockoff  = (int*)(ws + alloc(SCAN_NB * 4));

  // Build dst-sorted CSR (self-loops handled implicitly via sal)
  k_zero<<<(NNODES + 255) / 256, 256, 0, stream>>>(fill, NNODES);
  k_hist<<<(NEDGES + 255) / 256, 256, 0, stream>>>(dstA, fill, NEDGES);
  k_scan1<<<SCAN_NB, 256, 0, stream>>>(fill, row_start, blocksum, NNODES);
  k_scan2<<<1, 128, 0, stream>>>(blocksum, blockoff, row_start, SCAN_NB, NNODES);
  k_scan3<<<SCAN_NB, 256, 0, stream>>>(row_start, blockoff, fill, NNODES);
  k_scatter<<<(NEDGES + 255) / 256, 256, 0, stream>>>(srcA, dstA, row_start, fill, csr, NEDGES);

  int gM = (NNODES + 31) / 32;

  // ---- layer 0 (IN=128 -> 4x64, concat) ----
  k_cvt_pack<<<(NNODES * 4 + 255) / 256, 256, 0, stream>>>(x, Ahp, Alp, NNODES * 4);
  k_prep_w<<<(256 * 4 + 255) / 256, 256, 0, stream>>>(lin0, wh, wl, 128, 256);
  k_gemm_mfma<128, 4, 4><<<gM, 256, 0, stream>>>(Ahp, Alp, wh, wl, as0, ad0, h16, vas, vad, NNODES, 256);
  k_alpha4<<<5000, 256, 0, stream>>>(vas, vad, row_start, csr, el, sal);
  k_gath4<<<5000, 256, 0, stream>>>(h16, row_start, csr, el, sal, b0, Ahp, Alp);

  // ---- layer 1 (256 -> 4x64, concat) ----
  k_prep_w<<<(256 * 8 + 255) / 256, 256, 0, stream>>>(lin1, wh, wl, 256, 256);
  k_gemm_mfma<256, 4, 4><<<gM, 256, 0, stream>>>(Ahp, Alp, wh, wl, as1, ad1, h16, vas, vad, NNODES, 256);
  k_alpha4<<<5000, 256, 0, stream>>>(vas, vad, row_start, csr, el, sal);
  k_gath4<<<5000, 256, 0, stream>>>(h16, row_start, csr, el, sal, b1l, Ahp, Alp);

  // ---- layer 2 (256 -> 64, 1 head, mean) + MLP ----
  k_prep_w<<<(64 * 8 + 255) / 256, 256, 0, stream>>>(lin2, wh, wl, 256, 64);
  k_gemm_mfma<256, 1, 1><<<gM, 256, 0, stream>>>(Ahp, Alp, wh, wl, as2, ad2, h16, vas, vad, NNODES, 64);
  k_alpha1<<<5000, 256, 0, stream>>>(vas, vad, row_start, csr, el, sal);
  k_gath1<<<5000, 256, 0, stream>>>(h16, row_start, csr, el, sal, b2l, w1, mb1, w2, mb2, outp);
}